// Round 7
// baseline (325.565 us; speedup 1.0000x reference)
//
#include <hip/hip_runtime.h>

#define N_NODES 50000
#define E_EDGES 800000
#define LRELU 0.2f
#define LN_EPS 1e-5f
#define NBUCK 98              // ceil(50000/512)
#define BSHIFT 9              // 512 nodes per bucket

typedef short bf16x8 __attribute__((ext_vector_type(8)));
typedef float f32x4 __attribute__((ext_vector_type(4)));

__device__ __forceinline__ ushort f2bf(float f) {
    uint u = __float_as_uint(f);
    u += 0x7FFF + ((u >> 16) & 1);          // RNE
    return (ushort)(u >> 16);
}
__device__ __forceinline__ float bflo(uint u) { return __uint_as_float(u << 16); }
__device__ __forceinline__ float bfhi(uint u) { return __uint_as_float(u & 0xFFFF0000u); }

// ---------------------------------------------------------------------------
// CSR stage 1: per-bucket edge counts (LDS hist -> global atomics)
// ---------------------------------------------------------------------------
__global__ __launch_bounds__(256) void bucket_count_kernel(
    const int* __restrict__ dst, int* __restrict__ bucketCnt, int e)
{
    __shared__ int lhist[NBUCK];
    int t = threadIdx.x;
    if (t < NBUCK) lhist[t] = 0;
    __syncthreads();
    int e0 = blockIdx.x * 2048;
    int count = min(2048, e - e0);
    #pragma unroll
    for (int q = 0; q < 8; ++q) {
        int li = t + q * 256;
        if (li < count) atomicAdd(&lhist[dst[e0 + li] >> BSHIFT], 1);
    }
    __syncthreads();
    if (t < NBUCK && lhist[t]) atomicAdd(&bucketCnt[t], lhist[t]);
}

// ---------------------------------------------------------------------------
// CSR stage 2: exclusive scan of 98 bucket counts (1 block, 128 threads)
// ---------------------------------------------------------------------------
__global__ __launch_bounds__(128) void bucket_scan_kernel(
    const int* __restrict__ bucketCnt, int* __restrict__ bucketBase,
    int* __restrict__ bucketCursor)
{
    __shared__ int ls[128];
    int t = threadIdx.x;
    int v = (t < NBUCK) ? bucketCnt[t] : 0;
    ls[t] = v;
    __syncthreads();
    #pragma unroll
    for (int off = 1; off < 128; off <<= 1) {
        int u = (t >= off) ? ls[t - off] : 0;
        __syncthreads();
        ls[t] += u;
        __syncthreads();
    }
    if (t < NBUCK) {
        int ex = ls[t] - v;
        bucketBase[t] = ex;
        bucketCursor[t] = ex;
    }
    if (t == NBUCK - 1) bucketBase[NBUCK] = ls[t];
}

// ---------------------------------------------------------------------------
// CSR stage 3: grouped scatter into bucket regions (full-line writebacks).
// pairs word = src (16b) | dstLow (9b) << 16.
// ---------------------------------------------------------------------------
__global__ __launch_bounds__(256) void bucket_scatter_kernel(
    const int* __restrict__ src, const int* __restrict__ dst,
    int* __restrict__ bucketCursor, uint* __restrict__ pairs, int e)
{
    __shared__ int lhist[128];
    __shared__ int lscan[NBUCK];
    __shared__ int lcur[NBUCK];
    __shared__ int lbase[NBUCK];
    __shared__ uint stageW[2048];
    __shared__ int  stageA[2048];
    int t = threadIdx.x;
    int e0 = blockIdx.x * 2048;
    int count = min(2048, e - e0);

    if (t < 128) lhist[t] = 0;
    if (t < NBUCK) lcur[t] = 0;
    __syncthreads();

    int  bb[8];
    uint pk[8];
    #pragma unroll
    for (int q = 0; q < 8; ++q) {
        int li = t + q * 256;
        if (li < count) {
            int d = dst[e0 + li];
            int s = src[e0 + li];
            bb[q] = d >> BSHIFT;
            pk[q] = (uint)s | ((uint)(d & 511) << 16);
            atomicAdd(&lhist[bb[q]], 1);
        } else bb[q] = -1;
    }
    __syncthreads();

    int orig = (t < 128) ? lhist[t] : 0;
    #pragma unroll
    for (int off = 1; off < 128; off <<= 1) {
        int u = 0;
        if (t < 128 && t >= off) u = lhist[t - off];
        __syncthreads();
        if (t < 128) lhist[t] += u;
        __syncthreads();
    }
    if (t < NBUCK) {
        lscan[t] = lhist[t] - orig;                       // exclusive
        lbase[t] = orig ? atomicAdd(&bucketCursor[t], orig) : 0;
    }
    __syncthreads();

    #pragma unroll
    for (int q = 0; q < 8; ++q) {
        if (bb[q] >= 0) {
            int slot = lscan[bb[q]] + atomicAdd(&lcur[bb[q]], 1);
            stageW[slot] = pk[q];
            stageA[slot] = lbase[bb[q]] + (slot - lscan[bb[q]]);
        }
    }
    __syncthreads();

    #pragma unroll
    for (int q = 0; q < 8; ++q) {
        int li = t + q * 256;
        if (li < count) pairs[stageA[li]] = stageW[li];
    }
}

// ---------------------------------------------------------------------------
// CSR stage 4: per-bucket sort -> offs[] + srcSorted (ushort).
// ---------------------------------------------------------------------------
__global__ __launch_bounds__(512) void bucket_sort_kernel(
    const uint* __restrict__ pairs, const int* __restrict__ bucketBase,
    int* __restrict__ offs, ushort* __restrict__ srcSorted, int n, int e)
{
    __shared__ int cnt[512], cur[512], ls[512];
    int b = blockIdx.x, t = threadIdx.x;
    int base = bucketBase[b];
    int m = bucketBase[b + 1] - base;
    cnt[t] = 0; cur[t] = 0;
    __syncthreads();
    for (int i = t; i < m; i += 512)
        atomicAdd(&cnt[pairs[base + i] >> 16], 1);
    __syncthreads();
    int orig = cnt[t];
    ls[t] = orig;
    __syncthreads();
    #pragma unroll
    for (int off = 1; off < 512; off <<= 1) {
        int u = (t >= off) ? ls[t - off] : 0;
        __syncthreads();
        ls[t] += u;
        __syncthreads();
    }
    int excl = ls[t] - orig;
    int node = (b << BSHIFT) + t;
    if (node < n) offs[node] = base + excl;
    if (b == NBUCK - 1 && t == 0) offs[n] = e;
    cnt[t] = excl;
    __syncthreads();
    for (int i = t; i < m; i += 512) {
        uint w = pairs[base + i];
        int dl = w >> 16;
        int pos = cnt[dl] + atomicAdd(&cur[dl], 1);
        srcSorted[base + pos] = (ushort)(w & 0xFFFFu);
    }
}

// ---------------------------------------------------------------------------
// Weight prep for BOTH layers, one dispatch.
// ---------------------------------------------------------------------------
__global__ __launch_bounds__(256) void prep_all_kernel(
    const float* __restrict__ W1s, const float* __restrict__ Wl1,
    const float* __restrict__ W1d, const float* __restrict__ a1s,
    const float* __restrict__ a1d,
    const float* __restrict__ W2s, const float* __restrict__ Wl2,
    const float* __restrict__ W2d, const float* __restrict__ a2s,
    const float* __restrict__ a2d,
    ushort* __restrict__ Wt, ushort* __restrict__ Watt)
{
    int t = threadIdx.x;
    if (blockIdx.x < 256) {
        int idx = blockIdx.x * 256 + t;          // [0,65536)
        int lw = idx >> 14, rem = idx & 16383;
        int nn = rem >> 7, k = rem & 127;
        const float* W = (lw == 0) ? W1s : (lw == 1) ? Wl1 : (lw == 2) ? W2s : Wl2;
        Wt[idx] = f2bf(W[k * 128 + nn]);
    } else {
        int L = blockIdx.x - 256;
        const float* Ws = L ? W2s : W1s;
        const float* Wd = L ? W2d : W1d;
        const float* as = L ? a2s : a1s;
        const float* adv = L ? a2d : a1d;
        #pragma unroll
        for (int q = 0; q < 8; ++q) {
            int e = q * 256 + t;                 // [0,2048)
            int c = e >> 7, f = e & 127;
            float v = 0.f;
            if (c < 8) {
                const float* W  = (c < 4) ? Ws : Wd;
                const float* av = (c < 4) ? as : adv;
                int h = c & 3;
                #pragma unroll
                for (int j = 0; j < 32; ++j)
                    v += W[f * 128 + h * 32 + j] * av[h * 32 + j];
            }
            Watt[L * 2048 + c * 128 + f] = f2bf(v);
        }
    }
}

// ---------------------------------------------------------------------------
// MFMA GEMM + fused attention-score tile. (unchanged from R6)
// ---------------------------------------------------------------------------
template <int LAYER>
__global__ __launch_bounds__(256) void gemm_fused_kernel(
    const float* __restrict__ Afp, const ushort* __restrict__ Abf,
    const ushort* __restrict__ Wt, const ushort* __restrict__ Watt,
    ushort* __restrict__ Cbf, float* __restrict__ a_sd, int n)
{
    __shared__ ushort Asb[64][136];
    __shared__ ushort Wsb[128][136];
    __shared__ ushort Attb[16][136];
    const int z = blockIdx.x;
    const int row0 = blockIdx.y * 64;
    const int tid = threadIdx.x;

    if (LAYER == 0) {
        #pragma unroll
        for (int i = 0; i < 8; ++i) {
            int idx = tid + i * 256;
            int r = idx >> 5, c4 = idx & 31;
            int grow = row0 + r;
            float4 v = make_float4(0.f, 0.f, 0.f, 0.f);
            if (grow < n) v = *(const float4*)(Afp + (size_t)grow * 128 + c4 * 4);
            ushort4 o;
            o.x = f2bf(v.x); o.y = f2bf(v.y); o.z = f2bf(v.z); o.w = f2bf(v.w);
            *(ushort4*)&Asb[r][c4 * 4] = o;
        }
    } else {
        #pragma unroll
        for (int i = 0; i < 4; ++i) {
            int c = tid + i * 256;
            int r = c >> 4, o = c & 15;
            int grow = row0 + r;
            uint4 v = make_uint4(0, 0, 0, 0);
            if (grow < n) v = *(const uint4*)(Abf + (size_t)grow * 128 + o * 8);
            *(uint4*)&Asb[r][o * 8] = v;
        }
    }
    {
        const ushort* Wz = Wt + (size_t)(LAYER * 2 + z) * 16384;
        #pragma unroll
        for (int i = 0; i < 8; ++i) {
            int c = tid + i * 256;
            int r = c >> 4, o = c & 15;
            uint4 v = *(const uint4*)(Wz + r * 128 + o * 8);
            *(uint4*)&Wsb[r][o * 8] = v;
        }
    }
    if (z == 0) {
        int r = tid >> 4, o = tid & 15;
        uint4 v = *(const uint4*)(Watt + LAYER * 2048 + r * 128 + o * 8);
        *(uint4*)&Attb[r][o * 8] = v;
    }
    __syncthreads();

    const int w = tid >> 6, lane = tid & 63;
    const int wm = w >> 1, wn = w & 1;
    const int l15 = lane & 15, lg = lane >> 4;
    const bool doAtt = (z == 0) && (wn == 0);

    f32x4 acc[2][4];
    f32x4 accA[2];
    #pragma unroll
    for (int m = 0; m < 2; ++m) {
        accA[m] = (f32x4){0.f, 0.f, 0.f, 0.f};
        #pragma unroll
        for (int j = 0; j < 4; ++j)
            acc[m][j] = (f32x4){0.f, 0.f, 0.f, 0.f};
    }

    #pragma unroll
    for (int ks = 0; ks < 4; ++ks) {
        const int k0 = ks * 32 + 4 * lg;
        bf16x8 af[2], bfr[4];
        #pragma unroll
        for (int m = 0; m < 2; ++m) {
            const ushort* p = &Asb[wm * 32 + m * 16 + l15][k0];
            ushort4 lo = *(const ushort4*)p;
            ushort4 hi = *(const ushort4*)(p + 16);
            bf16x8 a;
            a[0] = (short)lo.x; a[1] = (short)lo.y; a[2] = (short)lo.z; a[3] = (short)lo.w;
            a[4] = (short)hi.x; a[5] = (short)hi.y; a[6] = (short)hi.z; a[7] = (short)hi.w;
            af[m] = a;
        }
        #pragma unroll
        for (int j = 0; j < 4; ++j) {
            const ushort* p = &Wsb[wn * 64 + j * 16 + l15][k0];
            ushort4 lo = *(const ushort4*)p;
            ushort4 hi = *(const ushort4*)(p + 16);
            bf16x8 b;
            b[0] = (short)lo.x; b[1] = (short)lo.y; b[2] = (short)lo.z; b[3] = (short)lo.w;
            b[4] = (short)hi.x; b[5] = (short)hi.y; b[6] = (short)hi.z; b[7] = (short)hi.w;
            bfr[j] = b;
        }
        #pragma unroll
        for (int m = 0; m < 2; ++m)
            #pragma unroll
            for (int j = 0; j < 4; ++j)
                acc[m][j] = __builtin_amdgcn_mfma_f32_16x16x32_bf16(
                    af[m], bfr[j], acc[m][j], 0, 0, 0);
        if (doAtt) {
            const ushort* p = &Attb[l15][k0];
            ushort4 lo = *(const ushort4*)p;
            ushort4 hi = *(const ushort4*)(p + 16);
            bf16x8 b;
            b[0] = (short)lo.x; b[1] = (short)lo.y; b[2] = (short)lo.z; b[3] = (short)lo.w;
            b[4] = (short)hi.x; b[5] = (short)hi.y; b[6] = (short)hi.z; b[7] = (short)hi.w;
            #pragma unroll
            for (int m = 0; m < 2; ++m)
                accA[m] = __builtin_amdgcn_mfma_f32_16x16x32_bf16(
                    af[m], b, accA[m], 0, 0, 0);
        }
    }

    #pragma unroll
    for (int m = 0; m < 2; ++m)
        #pragma unroll
        for (int j = 0; j < 4; ++j)
            #pragma unroll
            for (int r = 0; r < 4; ++r) {
                int grow = row0 + wm * 32 + m * 16 + lg * 4 + r;
                if (grow < n)
                    Cbf[(size_t)grow * 256 + z * 128 + wn * 64 + j * 16 + l15] =
                        f2bf(acc[m][j][r]);
            }
    if (doAtt && l15 < 8) {
        #pragma unroll
        for (int m = 0; m < 2; ++m)
            #pragma unroll
            for (int r = 0; r < 4; ++r) {
                int grow = row0 + wm * 32 + m * 16 + lg * 4 + r;
                if (grow < n) a_sd[(size_t)grow * 8 + l15] = accA[m][r];
            }
    }
}

// ---------------------------------------------------------------------------
// Fused softmax + aggregate + epilogue. One wave per dst node.
// Edge-parallel lanes: per 4-edge batch, lane = (edge j = lane>>4, chgrp g).
// Lane loads uint4 (16B) of edge j's xs row — fully coalesced. Lanes 0-15
// compute all (edge,head) exps; 1 shfl distributes. Cross-edge reduction once
// after the loop. Tail via ee=0 clamp (no divergence).
// MODE 0: +skip+b+bl -> LayerNorm -> ReLU -> hbf (bf16)
// MODE 1: +skip+b+bl -> out (fp32)
// ---------------------------------------------------------------------------
template <int MODE>
__global__ __launch_bounds__(256) void aggregate_fused_kernel(
    const ushort* __restrict__ srcSorted, const int* __restrict__ offs,
    const ushort* __restrict__ bufbf,   // [n][256] xs|skip (bf16)
    const float* __restrict__ a_sd,     // [n][8]: 0-3 a_s, 4-7 a_d
    const float* __restrict__ bias_a, const float* __restrict__ bias_l,
    const float* __restrict__ gamma, const float* __restrict__ beta,
    ushort* __restrict__ hbf, float* __restrict__ out, int n)
{
    int node = (blockIdx.x * blockDim.x + threadIdx.x) >> 6;
    int lane = threadIdx.x & 63;
    if (node >= n) return;
    int beg = offs[node], end = offs[node + 1];
    const int j = lane >> 4;            // edge slot 0..3
    const int g = lane & 15;            // channel group (8 ch)
    const int h = g >> 2;               // head of my channels
    const int je = lane & 3, he = lane >> 2;   // exp-lane coords (lane<16)

    float adh = 0.f;
    if (lane < 16) adh = a_sd[(size_t)node * 8 + 4 + he];

    float acc[8] = {};
    float denp = 0.f;                   // partial den on exp lanes

    for (int t = beg; t < end; t += 4) {
        int s = 0; float ee = 0.f;
        if (lane < 16) {
            int idx = t + je;
            int ic = (idx < end) ? idx : (end - 1);
            s = srcSorted[ic];
            float as = a_sd[(size_t)s * 8 + he];
            float e = as + adh;
            e = (e > 0.f) ? e : LRELU * e;
            ee = (idx < end) ? __expf(e) : 0.f;
            denp += ee;
        }
        int   sq  = __shfl(s, j);               // from exp lane (he=0, je=j)
        float eeq = __shfl(ee, h * 4 + j);      // from exp lane (he=h, je=j)
        uint4 xv = *(const uint4*)(bufbf + (size_t)sq * 256 + g * 8);
        acc[0] = fmaf(eeq, bflo(xv.x), acc[0]);
        acc[1] = fmaf(eeq, bfhi(xv.x), acc[1]);
        acc[2] = fmaf(eeq, bflo(xv.y), acc[2]);
        acc[3] = fmaf(eeq, bfhi(xv.y), acc[3]);
        acc[4] = fmaf(eeq, bflo(xv.z), acc[4]);
        acc[5] = fmaf(eeq, bfhi(xv.z), acc[5]);
        acc[6] = fmaf(eeq, bflo(xv.w), acc[6]);
        acc[7] = fmaf(eeq, bfhi(xv.w), acc[7]);
    }

    // reduce acc over edge slots (lane bits 4,5)
    #pragma unroll
    for (int c = 0; c < 8; ++c) {
        acc[c] += __shfl_xor(acc[c], 16);
        acc[c] += __shfl_xor(acc[c], 32);
    }
    // reduce den over je (bits 0,1): exp lane (he*4+je) -> den[he] on all 4
    denp += __shfl_xor(denp, 1);
    denp += __shfl_xor(denp, 2);

    if (lane < 16) {
        // lane g(=lane) holds channels 8g..8g+7; its own head he=g>>2 matches denp
        float inv = 1.f / (denp + 1e-16f);
        uint4 sk = *(const uint4*)(bufbf + (size_t)node * 256 + 128 + g * 8);
        float4 ba0 = *(const float4*)(bias_a + g * 8);
        float4 ba1 = *(const float4*)(bias_a + g * 8 + 4);
        float4 bl0 = *(const float4*)(bias_l + g * 8);
        float4 bl1 = *(const float4*)(bias_l + g * 8 + 4);
        float v[8];
        v[0] = acc[0] * inv + bflo(sk.x) + ba0.x + bl0.x;
        v[1] = acc[1] * inv + bfhi(sk.x) + ba0.y + bl0.y;
        v[2] = acc[2] * inv + bflo(sk.y) + ba0.z + bl0.z;
        v[3] = acc[3] * inv + bfhi(sk.y) + ba0.w + bl0.w;
        v[4] = acc[4] * inv + bflo(sk.z) + ba1.x + bl1.x;
        v[5] = acc[5] * inv + bfhi(sk.z) + ba1.y + bl1.y;
        v[6] = acc[6] * inv + bflo(sk.w) + ba1.z + bl1.z;
        v[7] = acc[7] * inv + bfhi(sk.w) + ba1.w + bl1.w;

        if (MODE == 0) {
            float sum = 0.f, sq = 0.f;
            #pragma unroll
            for (int c = 0; c < 8; ++c) { sum += v[c]; sq += v[c] * v[c]; }
            #pragma unroll
            for (int off = 1; off < 16; off <<= 1) {
                sum += __shfl_xor(sum, off);
                sq  += __shfl_xor(sq, off);
            }
            float mu = sum * (1.f / 128.f);
            float var = sq * (1.f / 128.f) - mu * mu;
            float rs = rsqrtf(var + LN_EPS);
            float4 gm0 = *(const float4*)(gamma + g * 8);
            float4 gm1 = *(const float4*)(gamma + g * 8 + 4);
            float4 bt0 = *(const float4*)(beta + g * 8);
            float4 bt1 = *(const float4*)(beta + g * 8 + 4);
            float o[8];
            o[0] = fmaxf((v[0] - mu) * rs * gm0.x + bt0.x, 0.f);
            o[1] = fmaxf((v[1] - mu) * rs * gm0.y + bt0.y, 0.f);
            o[2] = fmaxf((v[2] - mu) * rs * gm0.z + bt0.z, 0.f);
            o[3] = fmaxf((v[3] - mu) * rs * gm0.w + bt0.w, 0.f);
            o[4] = fmaxf((v[4] - mu) * rs * gm1.x + bt1.x, 0.f);
            o[5] = fmaxf((v[5] - mu) * rs * gm1.y + bt1.y, 0.f);
            o[6] = fmaxf((v[6] - mu) * rs * gm1.z + bt1.z, 0.f);
            o[7] = fmaxf((v[7] - mu) * rs * gm1.w + bt1.w, 0.f);
            uint4 st;
            st.x = (uint)f2bf(o[0]) | ((uint)f2bf(o[1]) << 16);
            st.y = (uint)f2bf(o[2]) | ((uint)f2bf(o[3]) << 16);
            st.z = (uint)f2bf(o[4]) | ((uint)f2bf(o[5]) << 16);
            st.w = (uint)f2bf(o[6]) | ((uint)f2bf(o[7]) << 16);
            *(uint4*)(hbf + (size_t)node * 128 + g * 8) = st;
        } else {
            *(float4*)(out + (size_t)node * 128 + g * 8) =
                make_float4(v[0], v[1], v[2], v[3]);
            *(float4*)(out + (size_t)node * 128 + g * 8 + 4) =
                make_float4(v[4], v[5], v[6], v[7]);
        }
    }
}

extern "C" void kernel_launch(void* const* d_in, const int* in_sizes, int n_in,
                              void* d_out, int out_size, void* d_ws, size_t ws_size,
                              hipStream_t stream) {
    const float* x       = (const float*)d_in[0];
    const int*   ei      = (const int*)d_in[1];
    const int*   src     = ei;
    const int*   dst     = ei + E_EDGES;
    const float* W1_src  = (const float*)d_in[2];
    const float* W1_dst  = (const float*)d_in[3];
    const float* att1_s  = (const float*)d_in[4];
    const float* att1_d  = (const float*)d_in[5];
    const float* b1      = (const float*)d_in[6];
    const float* Wl1     = (const float*)d_in[7];
    const float* bl1     = (const float*)d_in[8];
    const float* gamma   = (const float*)d_in[9];
    const float* beta    = (const float*)d_in[10];
    const float* W2_src  = (const float*)d_in[11];
    const float* W2_dst  = (const float*)d_in[12];
    const float* att2_s  = (const float*)d_in[13];
    const float* att2_d  = (const float*)d_in[14];
    const float* b2      = (const float*)d_in[15];
    const float* Wl2     = (const float*)d_in[16];
    const float* bl2     = (const float*)d_in[17];
    float* out = (float*)d_out;

    // workspace layout
    char* p = (char*)d_ws;
    float* a_sd        = (float*)p;      p += (size_t)N_NODES * 8 * 4;
    int* offs          = (int*)p;        p += (size_t)(N_NODES + 1) * 4;
    int* bucketCnt     = (int*)p;        p += (NBUCK) * 4;
    int* bucketBase    = (int*)p;        p += (NBUCK + 1) * 4;
    int* bucketCursor  = (int*)p;        p += (NBUCK + 1) * 4;
    uint* pairs        = (uint*)p;       p += (size_t)E_EDGES * 4;
    ushort* hbf        = (ushort*)p;     p += (size_t)N_NODES * 128 * 2;
    ushort* bufbf      = (ushort*)p;     p += (size_t)N_NODES * 256 * 2;
    ushort* Wt         = (ushort*)p;     p += (size_t)4 * 16384 * 2;
    ushort* Watt       = (ushort*)p;     p += (size_t)2 * 2048 * 2;
    ushort* srcSorted  = (ushort*)p;     p += (size_t)E_EDGES * 2;

    dim3 ggrid(2, (N_NODES + 63) / 64);
    int edge_blocks = (E_EDGES + 2047) / 2048;   // 391
    int wave_grid   = (N_NODES + 3) / 4;

    // -------- CSR build --------
    hipMemsetAsync(bucketCnt, 0, NBUCK * sizeof(int), stream);
    bucket_count_kernel<<<edge_blocks, 256, 0, stream>>>(dst, bucketCnt, E_EDGES);
    bucket_scan_kernel<<<1, 128, 0, stream>>>(bucketCnt, bucketBase, bucketCursor);
    bucket_scatter_kernel<<<edge_blocks, 256, 0, stream>>>(src, dst, bucketCursor, pairs, E_EDGES);
    bucket_sort_kernel<<<NBUCK, 512, 0, stream>>>(pairs, bucketBase, offs, srcSorted, N_NODES, E_EDGES);

    // -------- weight prep (both layers) --------
    prep_all_kernel<<<258, 256, 0, stream>>>(
        W1_src, Wl1, W1_dst, att1_s, att1_d,
        W2_src, Wl2, W2_dst, att2_s, att2_d, Wt, Watt);

    // -------- layer 1 --------
    gemm_fused_kernel<0><<<ggrid, 256, 0, stream>>>(x, nullptr, Wt, Watt, bufbf, a_sd, N_NODES);
    aggregate_fused_kernel<0><<<wave_grid, 256, 0, stream>>>(
        srcSorted, offs, bufbf, a_sd, b1, bl1, gamma, beta, hbf, nullptr, N_NODES);

    // -------- layer 2 --------
    gemm_fused_kernel<1><<<ggrid, 256, 0, stream>>>(nullptr, hbf, Wt, Watt, bufbf, a_sd, N_NODES);
    aggregate_fused_kernel<1><<<wave_grid, 256, 0, stream>>>(
        srcSorted, offs, bufbf, a_sd, b2, bl2, nullptr, nullptr, nullptr, out, N_NODES);
}

// Round 8
// 293.449 us; speedup vs baseline: 1.1094x; 1.1094x over previous
//
#include <hip/hip_runtime.h>

#define N_NODES 50000
#define E_EDGES 800000
#define LRELU 0.2f
#define LN_EPS 1e-5f
#define NBUCK 98              // ceil(50000/512)
#define BSHIFT 9              // 512 nodes per bucket
#define BCAP 9216             // per-bucket edge capacity (mean 8163, sigma~90)

typedef short bf16x8 __attribute__((ext_vector_type(8)));
typedef float f32x4 __attribute__((ext_vector_type(4)));

__device__ __forceinline__ ushort f2bf(float f) {
    uint u = __float_as_uint(f);
    u += 0x7FFF + ((u >> 16) & 1);          // RNE
    return (ushort)(u >> 16);
}
__device__ __forceinline__ float bflo(uint u) { return __uint_as_float(u << 16); }
__device__ __forceinline__ float bfhi(uint u) { return __uint_as_float(u & 0xFFFF0000u); }

// ---------------------------------------------------------------------------
// CSR stage 1: grouped scatter into fixed-capacity bucket regions.
// pairs word = src (16b) | dstLow (9b) << 16. Region b = pairs[b*BCAP ...].
// ---------------------------------------------------------------------------
__global__ __launch_bounds__(256) void bucket_scatter_kernel(
    const int* __restrict__ src, const int* __restrict__ dst,
    int* __restrict__ bucketCursor, uint* __restrict__ pairs, int e)
{
    __shared__ int lhist[128];
    __shared__ int lscan[NBUCK];
    __shared__ int lcur[NBUCK];
    __shared__ int lbase[NBUCK];
    __shared__ uint stageW[2048];
    __shared__ int  stageA[2048];
    int t = threadIdx.x;
    int e0 = blockIdx.x * 2048;
    int count = min(2048, e - e0);

    if (t < 128) lhist[t] = 0;
    if (t < NBUCK) lcur[t] = 0;
    __syncthreads();

    int  bb[8];
    uint pk[8];
    #pragma unroll
    for (int q = 0; q < 8; ++q) {
        int li = t + q * 256;
        if (li < count) {
            int d = dst[e0 + li];
            int s = src[e0 + li];
            bb[q] = d >> BSHIFT;
            pk[q] = (uint)s | ((uint)(d & 511) << 16);
            atomicAdd(&lhist[bb[q]], 1);
        } else bb[q] = -1;
    }
    __syncthreads();

    int orig = (t < 128) ? lhist[t] : 0;
    #pragma unroll
    for (int off = 1; off < 128; off <<= 1) {
        int u = 0;
        if (t < 128 && t >= off) u = lhist[t - off];
        __syncthreads();
        if (t < 128) lhist[t] += u;
        __syncthreads();
    }
    if (t < NBUCK) {
        lscan[t] = lhist[t] - orig;                       // exclusive
        lbase[t] = t * BCAP + (orig ? atomicAdd(&bucketCursor[t], orig) : 0);
    }
    __syncthreads();

    #pragma unroll
    for (int q = 0; q < 8; ++q) {
        if (bb[q] >= 0) {
            int slot = lscan[bb[q]] + atomicAdd(&lcur[bb[q]], 1);
            stageW[slot] = pk[q];
            stageA[slot] = lbase[bb[q]] + (slot - lscan[bb[q]]);
        }
    }
    __syncthreads();

    #pragma unroll
    for (int q = 0; q < 8; ++q) {
        int li = t + q * 256;
        if (li < count) pairs[stageA[li]] = stageW[li];
    }
}

// ---------------------------------------------------------------------------
// CSR stage 2: per-bucket sort. One block per bucket (512 threads).
// Emits offs[node] (bucket-strided), degs[node], srcSorted (ushort).
// ---------------------------------------------------------------------------
__global__ __launch_bounds__(512) void bucket_sort_kernel(
    const uint* __restrict__ pairs, const int* __restrict__ bucketCursor,
    int* __restrict__ offs, ushort* __restrict__ degs,
    ushort* __restrict__ srcSorted, int n)
{
    __shared__ int cnt[512], cur[512], ls[512];
    int b = blockIdx.x, t = threadIdx.x;
    int base = b * BCAP;
    int m = bucketCursor[b];
    cnt[t] = 0; cur[t] = 0;
    __syncthreads();
    for (int i = t; i < m; i += 512)
        atomicAdd(&cnt[pairs[base + i] >> 16], 1);
    __syncthreads();
    int orig = cnt[t];
    ls[t] = orig;
    __syncthreads();
    #pragma unroll
    for (int off = 1; off < 512; off <<= 1) {
        int u = (t >= off) ? ls[t - off] : 0;
        __syncthreads();
        ls[t] += u;
        __syncthreads();
    }
    int excl = ls[t] - orig;
    int node = (b << BSHIFT) + t;
    if (node < n) {
        offs[node] = base + excl;
        degs[node] = (ushort)orig;
    }
    cnt[t] = excl;
    __syncthreads();
    for (int i = t; i < m; i += 512) {
        uint w = pairs[base + i];
        int dl = w >> 16;
        int pos = cnt[dl] + atomicAdd(&cur[dl], 1);
        srcSorted[base + pos] = (ushort)(w & 0xFFFFu);
    }
}

// ---------------------------------------------------------------------------
// Weight prep for BOTH layers, one dispatch.
// ---------------------------------------------------------------------------
__global__ __launch_bounds__(256) void prep_all_kernel(
    const float* __restrict__ W1s, const float* __restrict__ Wl1,
    const float* __restrict__ W1d, const float* __restrict__ a1s,
    const float* __restrict__ a1d,
    const float* __restrict__ W2s, const float* __restrict__ Wl2,
    const float* __restrict__ W2d, const float* __restrict__ a2s,
    const float* __restrict__ a2d,
    ushort* __restrict__ Wt, ushort* __restrict__ Watt)
{
    int t = threadIdx.x;
    if (blockIdx.x < 256) {
        int idx = blockIdx.x * 256 + t;          // [0,65536)
        int lw = idx >> 14, rem = idx & 16383;
        int nn = rem >> 7, k = rem & 127;
        const float* W = (lw == 0) ? W1s : (lw == 1) ? Wl1 : (lw == 2) ? W2s : Wl2;
        Wt[idx] = f2bf(W[k * 128 + nn]);
    } else {
        int L = blockIdx.x - 256;
        const float* Ws = L ? W2s : W1s;
        const float* Wd = L ? W2d : W1d;
        const float* as = L ? a2s : a1s;
        const float* adv = L ? a2d : a1d;
        #pragma unroll
        for (int q = 0; q < 8; ++q) {
            int e = q * 256 + t;                 // [0,2048)
            int c = e >> 7, f = e & 127;
            float v = 0.f;
            if (c < 8) {
                const float* W  = (c < 4) ? Ws : Wd;
                const float* av = (c < 4) ? as : adv;
                int h = c & 3;
                #pragma unroll
                for (int j = 0; j < 32; ++j)
                    v += W[f * 128 + h * 32 + j] * av[h * 32 + j];
            }
            Watt[L * 2048 + c * 128 + f] = f2bf(v);
        }
    }
}

// ---------------------------------------------------------------------------
// MFMA GEMM + fused attention-score tile. C-write staged through LDS (reuses
// the A tile) for coalesced uint4 stores.
// ---------------------------------------------------------------------------
template <int LAYER>
__global__ __launch_bounds__(256) void gemm_fused_kernel(
    const float* __restrict__ Afp, const ushort* __restrict__ Abf,
    const ushort* __restrict__ Wt, const ushort* __restrict__ Watt,
    ushort* __restrict__ Cbf, float* __restrict__ a_sd, int n)
{
    __shared__ ushort Asb[64][136];
    __shared__ ushort Wsb[128][136];
    __shared__ ushort Attb[16][136];
    const int z = blockIdx.x;
    const int row0 = blockIdx.y * 64;
    const int tid = threadIdx.x;

    if (LAYER == 0) {
        #pragma unroll
        for (int i = 0; i < 8; ++i) {
            int idx = tid + i * 256;
            int r = idx >> 5, c4 = idx & 31;
            int grow = row0 + r;
            float4 v = make_float4(0.f, 0.f, 0.f, 0.f);
            if (grow < n) v = *(const float4*)(Afp + (size_t)grow * 128 + c4 * 4);
            ushort4 o;
            o.x = f2bf(v.x); o.y = f2bf(v.y); o.z = f2bf(v.z); o.w = f2bf(v.w);
            *(ushort4*)&Asb[r][c4 * 4] = o;
        }
    } else {
        #pragma unroll
        for (int i = 0; i < 4; ++i) {
            int c = tid + i * 256;
            int r = c >> 4, o = c & 15;
            int grow = row0 + r;
            uint4 v = make_uint4(0, 0, 0, 0);
            if (grow < n) v = *(const uint4*)(Abf + (size_t)grow * 128 + o * 8);
            *(uint4*)&Asb[r][o * 8] = v;
        }
    }
    {
        const ushort* Wz = Wt + (size_t)(LAYER * 2 + z) * 16384;
        #pragma unroll
        for (int i = 0; i < 8; ++i) {
            int c = tid + i * 256;
            int r = c >> 4, o = c & 15;
            uint4 v = *(const uint4*)(Wz + r * 128 + o * 8);
            *(uint4*)&Wsb[r][o * 8] = v;
        }
    }
    if (z == 0) {
        int r = tid >> 4, o = tid & 15;
        uint4 v = *(const uint4*)(Watt + LAYER * 2048 + r * 128 + o * 8);
        *(uint4*)&Attb[r][o * 8] = v;
    }
    __syncthreads();

    const int w = tid >> 6, lane = tid & 63;
    const int wm = w >> 1, wn = w & 1;
    const int l15 = lane & 15, lg = lane >> 4;
    const bool doAtt = (z == 0) && (wn == 0);

    f32x4 acc[2][4];
    f32x4 accA[2];
    #pragma unroll
    for (int m = 0; m < 2; ++m) {
        accA[m] = (f32x4){0.f, 0.f, 0.f, 0.f};
        #pragma unroll
        for (int j = 0; j < 4; ++j)
            acc[m][j] = (f32x4){0.f, 0.f, 0.f, 0.f};
    }

    #pragma unroll
    for (int ks = 0; ks < 4; ++ks) {
        const int k0 = ks * 32 + 4 * lg;
        bf16x8 af[2], bfr[4];
        #pragma unroll
        for (int m = 0; m < 2; ++m) {
            const ushort* p = &Asb[wm * 32 + m * 16 + l15][k0];
            ushort4 lo = *(const ushort4*)p;
            ushort4 hi = *(const ushort4*)(p + 16);
            bf16x8 a;
            a[0] = (short)lo.x; a[1] = (short)lo.y; a[2] = (short)lo.z; a[3] = (short)lo.w;
            a[4] = (short)hi.x; a[5] = (short)hi.y; a[6] = (short)hi.z; a[7] = (short)hi.w;
            af[m] = a;
        }
        #pragma unroll
        for (int j = 0; j < 4; ++j) {
            const ushort* p = &Wsb[wn * 64 + j * 16 + l15][k0];
            ushort4 lo = *(const ushort4*)p;
            ushort4 hi = *(const ushort4*)(p + 16);
            bf16x8 b;
            b[0] = (short)lo.x; b[1] = (short)lo.y; b[2] = (short)lo.z; b[3] = (short)lo.w;
            b[4] = (short)hi.x; b[5] = (short)hi.y; b[6] = (short)hi.z; b[7] = (short)hi.w;
            bfr[j] = b;
        }
        #pragma unroll
        for (int m = 0; m < 2; ++m)
            #pragma unroll
            for (int j = 0; j < 4; ++j)
                acc[m][j] = __builtin_amdgcn_mfma_f32_16x16x32_bf16(
                    af[m], bfr[j], acc[m][j], 0, 0, 0);
        if (doAtt) {
            const ushort* p = &Attb[l15][k0];
            ushort4 lo = *(const ushort4*)p;
            ushort4 hi = *(const ushort4*)(p + 16);
            bf16x8 b;
            b[0] = (short)lo.x; b[1] = (short)lo.y; b[2] = (short)lo.z; b[3] = (short)lo.w;
            b[4] = (short)hi.x; b[5] = (short)hi.y; b[6] = (short)hi.z; b[7] = (short)hi.w;
            #pragma unroll
            for (int m = 0; m < 2; ++m)
                accA[m] = __builtin_amdgcn_mfma_f32_16x16x32_bf16(
                    af[m], b, accA[m], 0, 0, 0);
        }
    }

    if (doAtt && l15 < 8) {
        #pragma unroll
        for (int m = 0; m < 2; ++m)
            #pragma unroll
            for (int r = 0; r < 4; ++r) {
                int grow = row0 + wm * 32 + m * 16 + lg * 4 + r;
                if (grow < n) a_sd[(size_t)grow * 8 + l15] = accA[m][r];
            }
    }

    // ---- stage C in LDS (reuse Asb), then coalesced stores ----
    __syncthreads();
    ushort (*Cs)[136] = (ushort(*)[136])&Asb[0][0];
    #pragma unroll
    for (int m = 0; m < 2; ++m)
        #pragma unroll
        for (int j = 0; j < 4; ++j)
            #pragma unroll
            for (int r = 0; r < 4; ++r)
                Cs[wm * 32 + m * 16 + lg * 4 + r][wn * 64 + j * 16 + l15] =
                    f2bf(acc[m][j][r]);
    __syncthreads();
    #pragma unroll
    for (int i = 0; i < 4; ++i) {
        int u4 = tid + i * 256;           // 1024 uint4s = 64 rows x 16
        int r = u4 >> 4, c8 = u4 & 15;
        int grow = row0 + r;
        if (grow < n) {
            uint4 v = *(const uint4*)&Cs[r][c8 * 8];
            *(uint4*)(Cbf + (size_t)grow * 256 + z * 128 + c8 * 8) = v;
        }
    }
}

// ---------------------------------------------------------------------------
// Fused softmax + aggregate + epilogue. One wave per dst node.
// 8-edge batches: lanes 0-31 compute exps for (edge q=lane&7, head lane>>3);
// each lane gathers TWO independent uint4 rows per iter (edges j and j+4) —
// 2x memory-level parallelism. Cross-edge reduce once after the loop.
// MODE 0: +skip+b+bl -> LayerNorm -> ReLU -> hbf (bf16)
// MODE 1: +skip+b+bl -> out (fp32)
// ---------------------------------------------------------------------------
template <int MODE>
__global__ __launch_bounds__(256) void aggregate_fused_kernel(
    const ushort* __restrict__ srcSorted, const int* __restrict__ offs,
    const ushort* __restrict__ degs,
    const ushort* __restrict__ bufbf,   // [n][256] xs|skip (bf16)
    const float* __restrict__ a_sd,     // [n][8]: 0-3 a_s, 4-7 a_d
    const float* __restrict__ bias_a, const float* __restrict__ bias_l,
    const float* __restrict__ gamma, const float* __restrict__ beta,
    ushort* __restrict__ hbf, float* __restrict__ out, int n)
{
    int node = (blockIdx.x * blockDim.x + threadIdx.x) >> 6;
    int lane = threadIdx.x & 63;
    if (node >= n) return;
    int beg = offs[node];
    int end = beg + degs[node];
    const int j = lane >> 4;            // gather edge slot 0..3
    const int g = lane & 15;            // channel group (8 ch)
    const int h = g >> 2;               // head of my channels
    const int he2 = (lane >> 3) & 3;    // exp-lane head (lanes 0-31)

    float adh = 0.f;
    if (lane < 32) adh = a_sd[(size_t)node * 8 + 4 + he2];

    float acc[8] = {};
    float denp = 0.f;                   // partial den on exp lanes

    for (int t = beg; t < end; t += 8) {
        int s = 0; float ee = 0.f;
        if (lane < 32) {
            int idx = t + (lane & 7);
            int ic = (idx < end) ? idx : (end - 1);
            s = srcSorted[ic];
            float as = a_sd[(size_t)s * 8 + he2];
            float e = as + adh;
            e = (e > 0.f) ? e : LRELU * e;
            ee = (idx < end) ? __expf(e) : 0.f;
            denp += ee;
        }
        int   sA  = __shfl(s, j);
        int   sB  = __shfl(s, j + 4);
        float eeA = __shfl(ee, h * 8 + j);
        float eeB = __shfl(ee, h * 8 + j + 4);
        uint4 xA = *(const uint4*)(bufbf + (size_t)sA * 256 + g * 8);
        uint4 xB = *(const uint4*)(bufbf + (size_t)sB * 256 + g * 8);
        acc[0] = fmaf(eeA, bflo(xA.x), acc[0]);
        acc[1] = fmaf(eeA, bfhi(xA.x), acc[1]);
        acc[2] = fmaf(eeA, bflo(xA.y), acc[2]);
        acc[3] = fmaf(eeA, bfhi(xA.y), acc[3]);
        acc[4] = fmaf(eeA, bflo(xA.z), acc[4]);
        acc[5] = fmaf(eeA, bfhi(xA.z), acc[5]);
        acc[6] = fmaf(eeA, bflo(xA.w), acc[6]);
        acc[7] = fmaf(eeA, bfhi(xA.w), acc[7]);
        acc[0] = fmaf(eeB, bflo(xB.x), acc[0]);
        acc[1] = fmaf(eeB, bfhi(xB.x), acc[1]);
        acc[2] = fmaf(eeB, bflo(xB.y), acc[2]);
        acc[3] = fmaf(eeB, bfhi(xB.y), acc[3]);
        acc[4] = fmaf(eeB, bflo(xB.z), acc[4]);
        acc[5] = fmaf(eeB, bfhi(xB.z), acc[5]);
        acc[6] = fmaf(eeB, bflo(xB.w), acc[6]);
        acc[7] = fmaf(eeB, bfhi(xB.w), acc[7]);
    }

    // reduce acc over gather slots (lane bits 4,5)
    #pragma unroll
    for (int c = 0; c < 8; ++c) {
        acc[c] += __shfl_xor(acc[c], 16);
        acc[c] += __shfl_xor(acc[c], 32);
    }
    // reduce den over edge index (bits 0,1,2) within exp lanes
    denp += __shfl_xor(denp, 1);
    denp += __shfl_xor(denp, 2);
    denp += __shfl_xor(denp, 4);
    // channel lane g needs den of head g>>2, held at lane (g>>2)*8
    float den = __shfl(denp, (g >> 2) * 8);

    if (lane < 16) {
        float inv = 1.f / (den + 1e-16f);
        uint4 sk = *(const uint4*)(bufbf + (size_t)node * 256 + 128 + g * 8);
        float4 ba0 = *(const float4*)(bias_a + g * 8);
        float4 ba1 = *(const float4*)(bias_a + g * 8 + 4);
        float4 bl0 = *(const float4*)(bias_l + g * 8);
        float4 bl1 = *(const float4*)(bias_l + g * 8 + 4);
        float v[8];
        v[0] = acc[0] * inv + bflo(sk.x) + ba0.x + bl0.x;
        v[1] = acc[1] * inv + bfhi(sk.x) + ba0.y + bl0.y;
        v[2] = acc[2] * inv + bflo(sk.y) + ba0.z + bl0.z;
        v[3] = acc[3] * inv + bfhi(sk.y) + ba0.w + bl0.w;
        v[4] = acc[4] * inv + bflo(sk.z) + ba1.x + bl1.x;
        v[5] = acc[5] * inv + bfhi(sk.z) + ba1.y + bl1.y;
        v[6] = acc[6] * inv + bflo(sk.w) + ba1.z + bl1.z;
        v[7] = acc[7] * inv + bfhi(sk.w) + ba1.w + bl1.w;

        if (MODE == 0) {
            float sum = 0.f, sq = 0.f;
            #pragma unroll
            for (int c = 0; c < 8; ++c) { sum += v[c]; sq += v[c] * v[c]; }
            #pragma unroll
            for (int off = 1; off < 16; off <<= 1) {
                sum += __shfl_xor(sum, off);
                sq  += __shfl_xor(sq, off);
            }
            float mu = sum * (1.f / 128.f);
            float var = sq * (1.f / 128.f) - mu * mu;
            float rs = rsqrtf(var + LN_EPS);
            float4 gm0 = *(const float4*)(gamma + g * 8);
            float4 gm1 = *(const float4*)(gamma + g * 8 + 4);
            float4 bt0 = *(const float4*)(beta + g * 8);
            float4 bt1 = *(const float4*)(beta + g * 8 + 4);
            float o[8];
            o[0] = fmaxf((v[0] - mu) * rs * gm0.x + bt0.x, 0.f);
            o[1] = fmaxf((v[1] - mu) * rs * gm0.y + bt0.y, 0.f);
            o[2] = fmaxf((v[2] - mu) * rs * gm0.z + bt0.z, 0.f);
            o[3] = fmaxf((v[3] - mu) * rs * gm0.w + bt0.w, 0.f);
            o[4] = fmaxf((v[4] - mu) * rs * gm1.x + bt1.x, 0.f);
            o[5] = fmaxf((v[5] - mu) * rs * gm1.y + bt1.y, 0.f);
            o[6] = fmaxf((v[6] - mu) * rs * gm1.z + bt1.z, 0.f);
            o[7] = fmaxf((v[7] - mu) * rs * gm1.w + bt1.w, 0.f);
            uint4 st;
            st.x = (uint)f2bf(o[0]) | ((uint)f2bf(o[1]) << 16);
            st.y = (uint)f2bf(o[2]) | ((uint)f2bf(o[3]) << 16);
            st.z = (uint)f2bf(o[4]) | ((uint)f2bf(o[5]) << 16);
            st.w = (uint)f2bf(o[6]) | ((uint)f2bf(o[7]) << 16);
            *(uint4*)(hbf + (size_t)node * 128 + g * 8) = st;
        } else {
            *(float4*)(out + (size_t)node * 128 + g * 8) =
                make_float4(v[0], v[1], v[2], v[3]);
            *(float4*)(out + (size_t)node * 128 + g * 8 + 4) =
                make_float4(v[4], v[5], v[6], v[7]);
        }
    }
}

extern "C" void kernel_launch(void* const* d_in, const int* in_sizes, int n_in,
                              void* d_out, int out_size, void* d_ws, size_t ws_size,
                              hipStream_t stream) {
    const float* x       = (const float*)d_in[0];
    const int*   ei      = (const int*)d_in[1];
    const int*   src     = ei;
    const int*   dst     = ei + E_EDGES;
    const float* W1_src  = (const float*)d_in[2];
    const float* W1_dst  = (const float*)d_in[3];
    const float* att1_s  = (const float*)d_in[4];
    const float* att1_d  = (const float*)d_in[5];
    const float* b1      = (const float*)d_in[6];
    const float* Wl1     = (const float*)d_in[7];
    const float* bl1     = (const float*)d_in[8];
    const float* gamma   = (const float*)d_in[9];
    const float* beta    = (const float*)d_in[10];
    const float* W2_src  = (const float*)d_in[11];
    const float* W2_dst  = (const float*)d_in[12];
    const float* att2_s  = (const float*)d_in[13];
    const float* att2_d  = (const float*)d_in[14];
    const float* b2      = (const float*)d_in[15];
    const float* Wl2     = (const float*)d_in[16];
    const float* bl2     = (const float*)d_in[17];
    float* out = (float*)d_out;

    // workspace layout
    char* p = (char*)d_ws;
    float* a_sd        = (float*)p;      p += (size_t)N_NODES * 8 * 4;
    int* offs          = (int*)p;        p += (size_t)N_NODES * 4;
    int* bucketCursor  = (int*)p;        p += 128 * 4;
    uint* pairs        = (uint*)p;       p += (size_t)NBUCK * BCAP * 4;
    ushort* degs       = (ushort*)p;     p += (size_t)N_NODES * 2;
    ushort* hbf        = (ushort*)p;     p += (size_t)N_NODES * 128 * 2;
    ushort* bufbf      = (ushort*)p;     p += (size_t)N_NODES * 256 * 2;
    ushort* Wt         = (ushort*)p;     p += (size_t)4 * 16384 * 2;
    ushort* Watt       = (ushort*)p;     p += (size_t)2 * 2048 * 2;
    ushort* srcSorted  = (ushort*)p;     p += (size_t)NBUCK * BCAP * 2;

    dim3 ggrid(2, (N_NODES + 63) / 64);
    int edge_blocks = (E_EDGES + 2047) / 2048;   // 391
    int wave_grid   = (N_NODES + 3) / 4;

    // -------- CSR build (fixed-capacity buckets) --------
    hipMemsetAsync(bucketCursor, 0, NBUCK * sizeof(int), stream);
    bucket_scatter_kernel<<<edge_blocks, 256, 0, stream>>>(src, dst, bucketCursor, pairs, E_EDGES);
    bucket_sort_kernel<<<NBUCK, 512, 0, stream>>>(pairs, bucketCursor, offs, degs, srcSorted, N_NODES);

    // -------- weight prep (both layers) --------
    prep_all_kernel<<<258, 256, 0, stream>>>(
        W1_src, Wl1, W1_dst, att1_s, att1_d,
        W2_src, Wl2, W2_dst, att2_s, att2_d, Wt, Watt);

    // -------- layer 1 --------
    gemm_fused_kernel<0><<<ggrid, 256, 0, stream>>>(x, nullptr, Wt, Watt, bufbf, a_sd, N_NODES);
    aggregate_fused_kernel<0><<<wave_grid, 256, 0, stream>>>(
        srcSorted, offs, degs, bufbf, a_sd, b1, bl1, gamma, beta, hbf, nullptr, N_NODES);

    // -------- layer 2 --------
    gemm_fused_kernel<1><<<ggrid, 256, 0, stream>>>(nullptr, hbf, Wt, Watt, bufbf, a_sd, N_NODES);
    aggregate_fused_kernel<1><<<wave_grid, 256, 0, stream>>>(
        srcSorted, offs, degs, bufbf, a_sd, b2, bl2, nullptr, nullptr, nullptr, out, N_NODES);
}

// Round 10
// 287.710 us; speedup vs baseline: 1.1316x; 1.0199x over previous
//
#include <hip/hip_runtime.h>

#define N_NODES 50000
#define E_EDGES 800000
#define LRELU 0.2f
#define LN_EPS 1e-5f
#define NBUCK 196             // ceil(50000/256)
#define BSHIFT 8              // 256 nodes per bucket
#define BCAP 4608             // per-bucket capacity (mean 4096, sigma 64)

typedef short bf16x8 __attribute__((ext_vector_type(8)));
typedef float f32x4 __attribute__((ext_vector_type(4)));

__device__ __forceinline__ ushort f2bf(float f) {
    uint u = __float_as_uint(f);
    u += 0x7FFF + ((u >> 16) & 1);          // RNE
    return (ushort)(u >> 16);
}
__device__ __forceinline__ float bflo(uint u) { return __uint_as_float(u << 16); }
__device__ __forceinline__ float bfhi(uint u) { return __uint_as_float(u & 0xFFFF0000u); }

// ---------------------------------------------------------------------------
// CSR stage 1: grouped scatter into fixed-capacity bucket regions.
// 4096 edges per block. pairs word = src (16b) | dstLow (8b) << 16.
// ---------------------------------------------------------------------------
__global__ __launch_bounds__(256) void bucket_scatter_kernel(
    const int* __restrict__ src, const int* __restrict__ dst,
    int* __restrict__ bucketCursor, uint* __restrict__ pairs, int e)
{
    __shared__ int lhist[256];
    __shared__ int lscan[NBUCK];
    __shared__ int lcur[NBUCK];
    __shared__ int lbase[NBUCK];
    __shared__ uint stageW[4096];
    __shared__ int  stageA[4096];
    int t = threadIdx.x;
    int e0 = blockIdx.x * 4096;
    int count = min(4096, e - e0);

    lhist[t] = 0;
    if (t < NBUCK) lcur[t] = 0;
    __syncthreads();

    int  bb[16];
    uint pk[16];
    #pragma unroll
    for (int q = 0; q < 16; ++q) {
        int li = t + q * 256;
        if (li < count) {
            int d = dst[e0 + li];
            int s = src[e0 + li];
            bb[q] = d >> BSHIFT;
            pk[q] = (uint)s | ((uint)(d & 255) << 16);
            atomicAdd(&lhist[bb[q]], 1);
        } else bb[q] = -1;
    }
    __syncthreads();

    int orig = lhist[t];
    #pragma unroll
    for (int off = 1; off < 256; off <<= 1) {
        int u = (t >= off) ? lhist[t - off] : 0;
        __syncthreads();
        lhist[t] += u;
        __syncthreads();
    }
    if (t < NBUCK) {
        lscan[t] = lhist[t] - orig;                       // exclusive
        lbase[t] = t * BCAP + (orig ? atomicAdd(&bucketCursor[t], orig) : 0);
    }
    __syncthreads();

    #pragma unroll
    for (int q = 0; q < 16; ++q) {
        if (bb[q] >= 0) {
            int slot = lscan[bb[q]] + atomicAdd(&lcur[bb[q]], 1);
            stageW[slot] = pk[q];
            stageA[slot] = lbase[bb[q]] + (slot - lscan[bb[q]]);
        }
    }
    __syncthreads();

    #pragma unroll
    for (int q = 0; q < 16; ++q) {
        int li = t + q * 256;
        if (li < count) pairs[stageA[li]] = stageW[li];
    }
}

// ---------------------------------------------------------------------------
// CSR stage 2: per-bucket sort. One block per bucket (256 threads).
// Emits offs[node] (bucket-strided), degs[node], srcSorted (ushort).
// ---------------------------------------------------------------------------
__global__ __launch_bounds__(256) void bucket_sort_kernel(
    const uint* __restrict__ pairs, const int* __restrict__ bucketCursor,
    int* __restrict__ offs, ushort* __restrict__ degs,
    ushort* __restrict__ srcSorted, int n)
{
    __shared__ int cnt[256], cur[256], ls[256];
    int b = blockIdx.x, t = threadIdx.x;
    int base = b * BCAP;
    int m = bucketCursor[b];
    cnt[t] = 0; cur[t] = 0;
    __syncthreads();
    for (int i = t; i < m; i += 256)
        atomicAdd(&cnt[pairs[base + i] >> 16], 1);
    __syncthreads();
    int orig = cnt[t];
    ls[t] = orig;
    __syncthreads();
    #pragma unroll
    for (int off = 1; off < 256; off <<= 1) {
        int u = (t >= off) ? ls[t - off] : 0;
        __syncthreads();
        ls[t] += u;
        __syncthreads();
    }
    int excl = ls[t] - orig;
    int node = (b << BSHIFT) + t;
    if (node < n) {
        offs[node] = base + excl;
        degs[node] = (ushort)orig;
    }
    cnt[t] = excl;
    __syncthreads();
    for (int i = t; i < m; i += 256) {
        uint w = pairs[base + i];
        int dl = w >> 16;
        int pos = cnt[dl] + atomicAdd(&cur[dl], 1);
        srcSorted[base + pos] = (ushort)(w & 0xFFFFu);
    }
}

// ---------------------------------------------------------------------------
// Weight prep for BOTH layers + bucketCursor zeroing, one dispatch.
// blocks 0..255: Wt; blocks 256,257: Watt L0/L1; block 258: zero cursor.
// ---------------------------------------------------------------------------
__global__ __launch_bounds__(256) void prep_all_kernel(
    const float* __restrict__ W1s, const float* __restrict__ Wl1,
    const float* __restrict__ W1d, const float* __restrict__ a1s,
    const float* __restrict__ a1d,
    const float* __restrict__ W2s, const float* __restrict__ Wl2,
    const float* __restrict__ W2d, const float* __restrict__ a2s,
    const float* __restrict__ a2d,
    ushort* __restrict__ Wt, ushort* __restrict__ Watt,
    int* __restrict__ bucketCursor)
{
    int t = threadIdx.x;
    if (blockIdx.x < 256) {
        int idx = blockIdx.x * 256 + t;          // [0,65536)
        int lw = idx >> 14, rem = idx & 16383;
        int nn = rem >> 7, k = rem & 127;
        const float* W = (lw == 0) ? W1s : (lw == 1) ? Wl1 : (lw == 2) ? W2s : Wl2;
        Wt[idx] = f2bf(W[k * 128 + nn]);
    } else if (blockIdx.x < 258) {
        int L = blockIdx.x - 256;
        const float* Ws = L ? W2s : W1s;
        const float* Wd = L ? W2d : W1d;
        const float* as = L ? a2s : a1s;
        const float* adv = L ? a2d : a1d;
        #pragma unroll
        for (int q = 0; q < 8; ++q) {
            int e = q * 256 + t;                 // [0,2048)
            int c = e >> 7, f = e & 127;
            float v = 0.f;
            if (c < 8) {
                const float* W  = (c < 4) ? Ws : Wd;
                const float* av = (c < 4) ? as : adv;
                int h = c & 3;
                #pragma unroll
                for (int j = 0; j < 32; ++j)
                    v += W[f * 128 + h * 32 + j] * av[h * 32 + j];
            }
            Watt[L * 2048 + c * 128 + f] = f2bf(v);
        }
    } else {
        if (t < NBUCK) bucketCursor[t] = 0;
    }
}

// ---------------------------------------------------------------------------
// MFMA GEMM + fused attention-score tile. C-write staged through LDS.
// ---------------------------------------------------------------------------
template <int LAYER>
__global__ __launch_bounds__(256) void gemm_fused_kernel(
    const float* __restrict__ Afp, const ushort* __restrict__ Abf,
    const ushort* __restrict__ Wt, const ushort* __restrict__ Watt,
    ushort* __restrict__ Cbf, float* __restrict__ a_sd, int n)
{
    __shared__ ushort Asb[64][136];
    __shared__ ushort Wsb[128][136];
    __shared__ ushort Attb[16][136];
    const int z = blockIdx.x;
    const int row0 = blockIdx.y * 64;
    const int tid = threadIdx.x;

    if (LAYER == 0) {
        #pragma unroll
        for (int i = 0; i < 8; ++i) {
            int idx = tid + i * 256;
            int r = idx >> 5, c4 = idx & 31;
            int grow = row0 + r;
            float4 v = make_float4(0.f, 0.f, 0.f, 0.f);
            if (grow < n) v = *(const float4*)(Afp + (size_t)grow * 128 + c4 * 4);
            ushort4 o;
            o.x = f2bf(v.x); o.y = f2bf(v.y); o.z = f2bf(v.z); o.w = f2bf(v.w);
            *(ushort4*)&Asb[r][c4 * 4] = o;
        }
    } else {
        #pragma unroll
        for (int i = 0; i < 4; ++i) {
            int c = tid + i * 256;
            int r = c >> 4, o = c & 15;
            int grow = row0 + r;
            uint4 v = make_uint4(0, 0, 0, 0);
            if (grow < n) v = *(const uint4*)(Abf + (size_t)grow * 128 + o * 8);
            *(uint4*)&Asb[r][o * 8] = v;
        }
    }
    {
        const ushort* Wz = Wt + (size_t)(LAYER * 2 + z) * 16384;
        #pragma unroll
        for (int i = 0; i < 8; ++i) {
            int c = tid + i * 256;
            int r = c >> 4, o = c & 15;
            uint4 v = *(const uint4*)(Wz + r * 128 + o * 8);
            *(uint4*)&Wsb[r][o * 8] = v;
        }
    }
    if (z == 0) {
        int r = tid >> 4, o = tid & 15;
        uint4 v = *(const uint4*)(Watt + LAYER * 2048 + r * 128 + o * 8);
        *(uint4*)&Attb[r][o * 8] = v;
    }
    __syncthreads();

    const int w = tid >> 6, lane = tid & 63;
    const int wm = w >> 1, wn = w & 1;
    const int l15 = lane & 15, lg = lane >> 4;
    const bool doAtt = (z == 0) && (wn == 0);

    f32x4 acc[2][4];
    f32x4 accA[2];
    #pragma unroll
    for (int m = 0; m < 2; ++m) {
        accA[m] = (f32x4){0.f, 0.f, 0.f, 0.f};
        #pragma unroll
        for (int j = 0; j < 4; ++j)
            acc[m][j] = (f32x4){0.f, 0.f, 0.f, 0.f};
    }

    #pragma unroll
    for (int ks = 0; ks < 4; ++ks) {
        const int k0 = ks * 32 + 4 * lg;
        bf16x8 af[2], bfr[4];
        #pragma unroll
        for (int m = 0; m < 2; ++m) {
            const ushort* p = &Asb[wm * 32 + m * 16 + l15][k0];
            ushort4 lo = *(const ushort4*)p;
            ushort4 hi = *(const ushort4*)(p + 16);
            bf16x8 a;
            a[0] = (short)lo.x; a[1] = (short)lo.y; a[2] = (short)lo.z; a[3] = (short)lo.w;
            a[4] = (short)hi.x; a[5] = (short)hi.y; a[6] = (short)hi.z; a[7] = (short)hi.w;
            af[m] = a;
        }
        #pragma unroll
        for (int j = 0; j < 4; ++j) {
            const ushort* p = &Wsb[wn * 64 + j * 16 + l15][k0];
            ushort4 lo = *(const ushort4*)p;
            ushort4 hi = *(const ushort4*)(p + 16);
            bf16x8 b;
            b[0] = (short)lo.x; b[1] = (short)lo.y; b[2] = (short)lo.z; b[3] = (short)lo.w;
            b[4] = (short)hi.x; b[5] = (short)hi.y; b[6] = (short)hi.z; b[7] = (short)hi.w;
            bfr[j] = b;
        }
        #pragma unroll
        for (int m = 0; m < 2; ++m)
            #pragma unroll
            for (int j = 0; j < 4; ++j)
                acc[m][j] = __builtin_amdgcn_mfma_f32_16x16x32_bf16(
                    af[m], bfr[j], acc[m][j], 0, 0, 0);
        if (doAtt) {
            const ushort* p = &Attb[l15][k0];
            ushort4 lo = *(const ushort4*)p;
            ushort4 hi = *(const ushort4*)(p + 16);
            bf16x8 b;
            b[0] = (short)lo.x; b[1] = (short)lo.y; b[2] = (short)lo.z; b[3] = (short)lo.w;
            b[4] = (short)hi.x; b[5] = (short)hi.y; b[6] = (short)hi.z; b[7] = (short)hi.w;
            #pragma unroll
            for (int m = 0; m < 2; ++m)
                accA[m] = __builtin_amdgcn_mfma_f32_16x16x32_bf16(
                    af[m], b, accA[m], 0, 0, 0);
        }
    }

    if (doAtt && l15 < 8) {
        #pragma unroll
        for (int m = 0; m < 2; ++m)
            #pragma unroll
            for (int r = 0; r < 4; ++r) {
                int grow = row0 + wm * 32 + m * 16 + lg * 4 + r;
                if (grow < n) a_sd[(size_t)grow * 8 + l15] = accA[m][r];
            }
    }

    // ---- stage C in LDS (reuse Asb), then coalesced stores ----
    __syncthreads();
    ushort (*Cs)[136] = (ushort(*)[136])&Asb[0][0];
    #pragma unroll
    for (int m = 0; m < 2; ++m)
        #pragma unroll
        for (int j = 0; j < 4; ++j)
            #pragma unroll
            for (int r = 0; r < 4; ++r)
                Cs[wm * 32 + m * 16 + lg * 4 + r][wn * 64 + j * 16 + l15] =
                    f2bf(acc[m][j][r]);
    __syncthreads();
    #pragma unroll
    for (int i = 0; i < 4; ++i) {
        int u4 = tid + i * 256;           // 1024 uint4s = 64 rows x 16
        int r = u4 >> 4, c8 = u4 & 15;
        int grow = row0 + r;
        if (grow < n) {
            uint4 v = *(const uint4*)&Cs[r][c8 * 8];
            *(uint4*)(Cbf + (size_t)grow * 256 + z * 128 + c8 * 8) = v;
        }
    }
}

// ---------------------------------------------------------------------------
// Fused softmax + aggregate + epilogue. One wave per dst node.
// 16-edge batches, zero idle lanes: every lane computes exp for
// (edge q=lane&15, head hh=lane>>4) — exactly E*4 exps. Channel lane
// (g=lane&15, j=lane>>4) gathers 4 independent uint4 rows (edges j,j+4,
// j+8,j+12). den: xor-reduce bits 0-3, broadcast from lane h*16.
// MODE 0: +skip+b+bl -> LayerNorm -> ReLU -> hbf (bf16)
// MODE 1: +skip+b+bl -> out (fp32)
// ---------------------------------------------------------------------------
template <int MODE>
__global__ __launch_bounds__(256) void aggregate_fused_kernel(
    const ushort* __restrict__ srcSorted, const int* __restrict__ offs,
    const ushort* __restrict__ degs,
    const ushort* __restrict__ bufbf,   // [n][256] xs|skip (bf16)
    const float* __restrict__ a_sd,     // [n][8]: 0-3 a_s, 4-7 a_d
    const float* __restrict__ bias_a, const float* __restrict__ bias_l,
    const float* __restrict__ gamma, const float* __restrict__ beta,
    ushort* __restrict__ hbf, float* __restrict__ out, int n)
{
    int node = (blockIdx.x * blockDim.x + threadIdx.x) >> 6;
    int lane = threadIdx.x & 63;
    if (node >= n) return;
    int beg = offs[node];
    int end = beg + degs[node];
    const int q  = lane & 15;           // exp edge slot
    const int hh = lane >> 4;           // exp head
    const int g  = lane & 15;           // channel group (8 ch)
    const int j  = lane >> 4;           // gather slot 0..3
    const int h  = g >> 2;              // head of my channels

    float adh = a_sd[(size_t)node * 8 + 4 + hh];

    float acc[8] = {};
    float denp = 0.f;

    for (int t = beg; t < end; t += 16) {
        int idx = t + q;
        int ic = (idx < end) ? idx : (end - 1);
        int s = srcSorted[ic];
        float as = a_sd[(size_t)s * 8 + hh];
        float e = as + adh;
        e = (e > 0.f) ? e : LRELU * e;
        float ee = (idx < end) ? __expf(e) : 0.f;
        denp += ee;

        int   sA  = __shfl(s, j);
        int   sB  = __shfl(s, j + 4);
        int   sC  = __shfl(s, j + 8);
        int   sD  = __shfl(s, j + 12);
        float eeA = __shfl(ee, h * 16 + j);
        float eeB = __shfl(ee, h * 16 + j + 4);
        float eeC = __shfl(ee, h * 16 + j + 8);
        float eeD = __shfl(ee, h * 16 + j + 12);
        uint4 xA = *(const uint4*)(bufbf + (size_t)sA * 256 + g * 8);
        uint4 xB = *(const uint4*)(bufbf + (size_t)sB * 256 + g * 8);
        uint4 xC = *(const uint4*)(bufbf + (size_t)sC * 256 + g * 8);
        uint4 xD = *(const uint4*)(bufbf + (size_t)sD * 256 + g * 8);
        acc[0] = fmaf(eeA, bflo(xA.x), acc[0]);
        acc[1] = fmaf(eeA, bfhi(xA.x), acc[1]);
        acc[2] = fmaf(eeA, bflo(xA.y), acc[2]);
        acc[3] = fmaf(eeA, bfhi(xA.y), acc[3]);
        acc[4] = fmaf(eeA, bflo(xA.z), acc[4]);
        acc[5] = fmaf(eeA, bfhi(xA.z), acc[5]);
        acc[6] = fmaf(eeA, bflo(xA.w), acc[6]);
        acc[7] = fmaf(eeA, bfhi(xA.w), acc[7]);
        acc[0] = fmaf(eeB, bflo(xB.x), acc[0]);
        acc[1] = fmaf(eeB, bfhi(xB.x), acc[1]);
        acc[2] = fmaf(eeB, bflo(xB.y), acc[2]);
        acc[3] = fmaf(eeB, bfhi(xB.y), acc[3]);
        acc[4] = fmaf(eeB, bflo(xB.z), acc[4]);
        acc[5] = fmaf(eeB, bfhi(xB.z), acc[5]);
        acc[6] = fmaf(eeB, bflo(xB.w), acc[6]);
        acc[7] = fmaf(eeB, bfhi(xB.w), acc[7]);
        acc[0] = fmaf(eeC, bflo(xC.x), acc[0]);
        acc[1] = fmaf(eeC, bfhi(xC.x), acc[1]);
        acc[2] = fmaf(eeC, bflo(xC.y), acc[2]);
        acc[3] = fmaf(eeC, bfhi(xC.y), acc[3]);
        acc[4] = fmaf(eeC, bflo(xC.z), acc[4]);
        acc[5] = fmaf(eeC, bfhi(xC.z), acc[5]);
        acc[6] = fmaf(eeC, bflo(xC.w), acc[6]);
        acc[7] = fmaf(eeC, bfhi(xC.w), acc[7]);
        acc[0] = fmaf(eeD, bflo(xD.x), acc[0]);
        acc[1] = fmaf(eeD, bfhi(xD.x), acc[1]);
        acc[2] = fmaf(eeD, bflo(xD.y), acc[2]);
        acc[3] = fmaf(eeD, bfhi(xD.y), acc[3]);
        acc[4] = fmaf(eeD, bflo(xD.z), acc[4]);
        acc[5] = fmaf(eeD, bfhi(xD.z), acc[5]);
        acc[6] = fmaf(eeD, bflo(xD.w), acc[6]);
        acc[7] = fmaf(eeD, bfhi(xD.w), acc[7]);
    }

    // reduce acc over gather slots (lane bits 4,5)
    #pragma unroll
    for (int c = 0; c < 8; ++c) {
        acc[c] += __shfl_xor(acc[c], 16);
        acc[c] += __shfl_xor(acc[c], 32);
    }
    // reduce den over edge slot q (bits 0-3); then broadcast head h's den
    denp += __shfl_xor(denp, 1);
    denp += __shfl_xor(denp, 2);
    denp += __shfl_xor(denp, 4);
    denp += __shfl_xor(denp, 8);
    float den = __shfl(denp, h * 16);

    if (lane < 16) {
        float inv = 1.f / (den + 1e-16f);
        uint4 sk = *(const uint4*)(bufbf + (size_t)node * 256 + 128 + g * 8);
        float4 ba0 = *(const float4*)(bias_a + g * 8);
        float4 ba1 = *(const float4*)(bias_a + g * 8 + 4);
        float4 bl0 = *(const float4*)(bias_l + g * 8);
        float4 bl1 = *(const float4*)(bias_l + g * 8 + 4);
        float v[8];
        v[0] = acc[0] * inv + bflo(sk.x) + ba0.x + bl0.x;
        v[1] = acc[1] * inv + bfhi(sk.x) + ba0.y + bl0.y;
        v[2] = acc[2] * inv + bflo(sk.y) + ba0.z + bl0.z;
        v[3] = acc[3] * inv + bfhi(sk.y) + ba0.w + bl0.w;
        v[4] = acc[4] * inv + bflo(sk.z) + ba1.x + bl1.x;
        v[5] = acc[5] * inv + bfhi(sk.z) + ba1.y + bl1.y;
        v[6] = acc[6] * inv + bflo(sk.w) + ba1.z + bl1.z;
        v[7] = acc[7] * inv + bfhi(sk.w) + ba1.w + bl1.w;

        if (MODE == 0) {
            float sum = 0.f, sq = 0.f;
            #pragma unroll
            for (int c = 0; c < 8; ++c) { sum += v[c]; sq += v[c] * v[c]; }
            #pragma unroll
            for (int off = 1; off < 16; off <<= 1) {
                sum += __shfl_xor(sum, off);
                sq  += __shfl_xor(sq, off);
            }
            float mu = sum * (1.f / 128.f);
            float var = sq * (1.f / 128.f) - mu * mu;
            float rs = rsqrtf(var + LN_EPS);
            float4 gm0 = *(const float4*)(gamma + g * 8);
            float4 gm1 = *(const float4*)(gamma + g * 8 + 4);
            float4 bt0 = *(const float4*)(beta + g * 8);
            float4 bt1 = *(const float4*)(beta + g * 8 + 4);
            float o[8];
            o[0] = fmaxf((v[0] - mu) * rs * gm0.x + bt0.x, 0.f);
            o[1] = fmaxf((v[1] - mu) * rs * gm0.y + bt0.y, 0.f);
            o[2] = fmaxf((v[2] - mu) * rs * gm0.z + bt0.z, 0.f);
            o[3] = fmaxf((v[3] - mu) * rs * gm0.w + bt0.w, 0.f);
            o[4] = fmaxf((v[4] - mu) * rs * gm1.x + bt1.x, 0.f);
            o[5] = fmaxf((v[5] - mu) * rs * gm1.y + bt1.y, 0.f);
            o[6] = fmaxf((v[6] - mu) * rs * gm1.z + bt1.z, 0.f);
            o[7] = fmaxf((v[7] - mu) * rs * gm1.w + bt1.w, 0.f);
            uint4 st;
            st.x = (uint)f2bf(o[0]) | ((uint)f2bf(o[1]) << 16);
            st.y = (uint)f2bf(o[2]) | ((uint)f2bf(o[3]) << 16);
            st.z = (uint)f2bf(o[4]) | ((uint)f2bf(o[5]) << 16);
            st.w = (uint)f2bf(o[6]) | ((uint)f2bf(o[7]) << 16);
            *(uint4*)(hbf + (size_t)node * 128 + g * 8) = st;
        } else {
            *(float4*)(out + (size_t)node * 128 + g * 8) =
                make_float4(v[0], v[1], v[2], v[3]);
            *(float4*)(out + (size_t)node * 128 + g * 8 + 4) =
                make_float4(v[4], v[5], v[6], v[7]);
        }
    }
}

extern "C" void kernel_launch(void* const* d_in, const int* in_sizes, int n_in,
                              void* d_out, int out_size, void* d_ws, size_t ws_size,
                              hipStream_t stream) {
    const float* x       = (const float*)d_in[0];
    const int*   ei      = (const int*)d_in[1];
    const int*   src     = ei;
    const int*   dst     = ei + E_EDGES;
    const float* W1_src  = (const float*)d_in[2];
    const float* W1_dst  = (const float*)d_in[3];
    const float* att1_s  = (const float*)d_in[4];
    const float* att1_d  = (const float*)d_in[5];
    const float* b1      = (const float*)d_in[6];
    const float* Wl1     = (const float*)d_in[7];
    const float* bl1     = (const float*)d_in[8];
    const float* gamma   = (const float*)d_in[9];
    const float* beta    = (const float*)d_in[10];
    const float* W2_src  = (const float*)d_in[11];
    const float* W2_dst  = (const float*)d_in[12];
    const float* att2_s  = (const float*)d_in[13];
    const float* att2_d  = (const float*)d_in[14];
    const float* b2      = (const float*)d_in[15];
    const float* Wl2     = (const float*)d_in[16];
    const float* bl2     = (const float*)d_in[17];
    float* out = (float*)d_out;

    // workspace layout
    char* p = (char*)d_ws;
    float* a_sd        = (float*)p;      p += (size_t)N_NODES * 8 * 4;
    int* offs          = (int*)p;        p += (size_t)N_NODES * 4;
    int* bucketCursor  = (int*)p;        p += 256 * 4;
    uint* pairs        = (uint*)p;       p += (size_t)NBUCK * BCAP * 4;
    ushort* degs       = (ushort*)p;     p += (size_t)N_NODES * 2;
    ushort* hbf        = (ushort*)p;     p += (size_t)N_NODES * 128 * 2;
    ushort* bufbf      = (ushort*)p;     p += (size_t)N_NODES * 256 * 2;
    ushort* Wt         = (ushort*)p;     p += (size_t)4 * 16384 * 2;
    ushort* Watt       = (ushort*)p;     p += (size_t)2 * 2048 * 2;
    ushort* srcSorted  = (ushort*)p;     p += (size_t)NBUCK * BCAP * 2;

    dim3 ggrid(2, (N_NODES + 63) / 64);
    int edge_blocks = (E_EDGES + 4095) / 4096;   // 196
    int wave_grid   = (N_NODES + 3) / 4;

    // -------- prep (weights + cursor zero), then CSR build --------
    prep_all_kernel<<<259, 256, 0, stream>>>(
        W1_src, Wl1, W1_dst, att1_s, att1_d,
        W2_src, Wl2, W2_dst, att2_s, att2_d, Wt, Watt, bucketCursor);
    bucket_scatter_kernel<<<edge_blocks, 256, 0, stream>>>(src, dst, bucketCursor, pairs, E_EDGES);
    bucket_sort_kernel<<<NBUCK, 256, 0, stream>>>(pairs, bucketCursor, offs, degs, srcSorted, N_NODES);

    // -------- layer 1 --------
    gemm_fused_kernel<0><<<ggrid, 256, 0, stream>>>(x, nullptr, Wt, Watt, bufbf, a_sd, N_NODES);
    aggregate_fused_kernel<0><<<wave_grid, 256, 0, stream>>>(
        srcSorted, offs, degs, bufbf, a_sd, b1, bl1, gamma, beta, hbf, nullptr, N_NODES);

    // -------- layer 2 --------
    gemm_fused_kernel<1><<<ggrid, 256, 0, stream>>>(nullptr, hbf, Wt, Watt, bufbf, a_sd, N_NODES);
    aggregate_fused_kernel<1><<<wave_grid, 256, 0, stream>>>(
        srcSorted, offs, degs, bufbf, a_sd, b2, bl2, nullptr, nullptr, nullptr, out, N_NODES);
}

// Round 11
// 282.407 us; speedup vs baseline: 1.1528x; 1.0188x over previous
//
#include <hip/hip_runtime.h>

#define N_NODES 50000
#define E_EDGES 800000
#define LRELU 0.2f
#define LN_EPS 1e-5f
#define NBUCK 196             // ceil(50000/256)
#define BSHIFT 8              // 256 nodes per bucket
#define BCAP 4608             // per-bucket capacity (mean 4096, sigma 64)

typedef short bf16x8 __attribute__((ext_vector_type(8)));
typedef float f32x4 __attribute__((ext_vector_type(4)));

__device__ __forceinline__ ushort f2bf(float f) {
    uint u = __float_as_uint(f);
    u += 0x7FFF + ((u >> 16) & 1);          // RNE
    return (ushort)(u >> 16);
}
__device__ __forceinline__ float bflo(uint u) { return __uint_as_float(u << 16); }
__device__ __forceinline__ float bfhi(uint u) { return __uint_as_float(u & 0xFFFF0000u); }

// ---------------------------------------------------------------------------
// CSR stage 1: grouped scatter into fixed-capacity bucket regions.
// 4096 edges per block. pairs word = src (16b) | dstLow (8b) << 16.
// ---------------------------------------------------------------------------
__global__ __launch_bounds__(256) void bucket_scatter_kernel(
    const int* __restrict__ src, const int* __restrict__ dst,
    int* __restrict__ bucketCursor, uint* __restrict__ pairs, int e)
{
    __shared__ int lhist[256];
    __shared__ int lscan[NBUCK];
    __shared__ int lcur[NBUCK];
    __shared__ int lbase[NBUCK];
    __shared__ int wsum[4];
    __shared__ uint stageW[4096];
    __shared__ int  stageA[4096];
    int t = threadIdx.x;
    int e0 = blockIdx.x * 4096;
    int count = min(4096, e - e0);

    lhist[t] = 0;
    if (t < NBUCK) lcur[t] = 0;
    __syncthreads();

    int  bb[16];
    uint pk[16];
    #pragma unroll
    for (int q = 0; q < 16; ++q) {
        int li = t + q * 256;
        if (li < count) {
            int d = dst[e0 + li];
            int s = src[e0 + li];
            bb[q] = d >> BSHIFT;
            pk[q] = (uint)s | ((uint)(d & 255) << 16);
            atomicAdd(&lhist[bb[q]], 1);
        } else bb[q] = -1;
    }
    __syncthreads();

    // wave-shuffle scan over 256 bucket counts (1 barrier)
    int orig = lhist[t];
    int lane64 = t & 63, wv = t >> 6;
    int incl = orig;
    #pragma unroll
    for (int off = 1; off < 64; off <<= 1) {
        int u = __shfl_up(incl, off);
        if (lane64 >= off) incl += u;
    }
    if (lane64 == 63) wsum[wv] = incl;
    __syncthreads();
    if (wv > 0) incl += wsum[0];
    if (wv > 1) incl += wsum[1];
    if (wv > 2) incl += wsum[2];
    if (t < NBUCK) {
        lscan[t] = incl - orig;                           // exclusive
        lbase[t] = t * BCAP + (orig ? atomicAdd(&bucketCursor[t], orig) : 0);
    }
    __syncthreads();

    #pragma unroll
    for (int q = 0; q < 16; ++q) {
        if (bb[q] >= 0) {
            int slot = lscan[bb[q]] + atomicAdd(&lcur[bb[q]], 1);
            stageW[slot] = pk[q];
            stageA[slot] = lbase[bb[q]] + (slot - lscan[bb[q]]);
        }
    }
    __syncthreads();

    #pragma unroll
    for (int q = 0; q < 16; ++q) {
        int li = t + q * 256;
        if (li < count) pairs[stageA[li]] = stageW[li];
    }
}

// ---------------------------------------------------------------------------
// CSR stage 2: per-bucket sort. One block per bucket (256 threads).
// Emits offs[node] (bucket-strided), degs[node], srcSorted (ushort).
// ---------------------------------------------------------------------------
__global__ __launch_bounds__(256) void bucket_sort_kernel(
    const uint* __restrict__ pairs, const int* __restrict__ bucketCursor,
    int* __restrict__ offs, ushort* __restrict__ degs,
    ushort* __restrict__ srcSorted, int n)
{
    __shared__ int cnt[256], cur[256];
    __shared__ int wsum[4];
    int b = blockIdx.x, t = threadIdx.x;
    int base = b * BCAP;
    int m = bucketCursor[b];
    cnt[t] = 0; cur[t] = 0;
    __syncthreads();
    for (int i = t; i < m; i += 256)
        atomicAdd(&cnt[pairs[base + i] >> 16], 1);
    __syncthreads();

    // wave-shuffle scan over 256 node counts (1 barrier)
    int orig = cnt[t];
    int lane64 = t & 63, wv = t >> 6;
    int incl = orig;
    #pragma unroll
    for (int off = 1; off < 64; off <<= 1) {
        int u = __shfl_up(incl, off);
        if (lane64 >= off) incl += u;
    }
    if (lane64 == 63) wsum[wv] = incl;
    __syncthreads();
    if (wv > 0) incl += wsum[0];
    if (wv > 1) incl += wsum[1];
    if (wv > 2) incl += wsum[2];
    int excl = incl - orig;

    int node = (b << BSHIFT) + t;
    if (node < n) {
        offs[node] = base + excl;
        degs[node] = (ushort)orig;
    }
    cnt[t] = excl;
    __syncthreads();
    for (int i = t; i < m; i += 256) {
        uint w = pairs[base + i];
        int dl = w >> 16;
        int pos = cnt[dl] + atomicAdd(&cur[dl], 1);
        srcSorted[base + pos] = (ushort)(w & 0xFFFFu);
    }
}

// ---------------------------------------------------------------------------
// Weight prep for BOTH layers + bucketCursor zeroing, one dispatch.
// blocks 0..255: Wt; blocks 256,257: Watt L0/L1; block 258: zero cursor.
// ---------------------------------------------------------------------------
__global__ __launch_bounds__(256) void prep_all_kernel(
    const float* __restrict__ W1s, const float* __restrict__ Wl1,
    const float* __restrict__ W1d, const float* __restrict__ a1s,
    const float* __restrict__ a1d,
    const float* __restrict__ W2s, const float* __restrict__ Wl2,
    const float* __restrict__ W2d, const float* __restrict__ a2s,
    const float* __restrict__ a2d,
    ushort* __restrict__ Wt, ushort* __restrict__ Watt,
    int* __restrict__ bucketCursor)
{
    int t = threadIdx.x;
    if (blockIdx.x < 256) {
        int idx = blockIdx.x * 256 + t;          // [0,65536)
        int lw = idx >> 14, rem = idx & 16383;
        int nn = rem >> 7, k = rem & 127;
        const float* W = (lw == 0) ? W1s : (lw == 1) ? Wl1 : (lw == 2) ? W2s : Wl2;
        Wt[idx] = f2bf(W[k * 128 + nn]);
    } else if (blockIdx.x < 258) {
        int L = blockIdx.x - 256;
        const float* Ws = L ? W2s : W1s;
        const float* Wd = L ? W2d : W1d;
        const float* as = L ? a2s : a1s;
        const float* adv = L ? a2d : a1d;
        #pragma unroll
        for (int q = 0; q < 8; ++q) {
            int e = q * 256 + t;                 // [0,2048)
            int c = e >> 7, f = e & 127;
            float v = 0.f;
            if (c < 8) {
                const float* W  = (c < 4) ? Ws : Wd;
                const float* av = (c < 4) ? as : adv;
                int h = c & 3;
                #pragma unroll
                for (int j = 0; j < 32; ++j)
                    v += W[f * 128 + h * 32 + j] * av[h * 32 + j];
            }
            Watt[L * 2048 + c * 128 + f] = f2bf(v);
        }
    } else {
        if (t < NBUCK) bucketCursor[t] = 0;
    }
}

// ---------------------------------------------------------------------------
// MFMA GEMM + fused attention-score tile. C-write staged through LDS.
// ---------------------------------------------------------------------------
template <int LAYER>
__global__ __launch_bounds__(256) void gemm_fused_kernel(
    const float* __restrict__ Afp, const ushort* __restrict__ Abf,
    const ushort* __restrict__ Wt, const ushort* __restrict__ Watt,
    ushort* __restrict__ Cbf, float* __restrict__ a_sd, int n)
{
    __shared__ ushort Asb[64][136];
    __shared__ ushort Wsb[128][136];
    __shared__ ushort Attb[16][136];
    const int z = blockIdx.x;
    const int row0 = blockIdx.y * 64;
    const int tid = threadIdx.x;

    if (LAYER == 0) {
        #pragma unroll
        for (int i = 0; i < 8; ++i) {
            int idx = tid + i * 256;
            int r = idx >> 5, c4 = idx & 31;
            int grow = row0 + r;
            float4 v = make_float4(0.f, 0.f, 0.f, 0.f);
            if (grow < n) v = *(const float4*)(Afp + (size_t)grow * 128 + c4 * 4);
            ushort4 o;
            o.x = f2bf(v.x); o.y = f2bf(v.y); o.z = f2bf(v.z); o.w = f2bf(v.w);
            *(ushort4*)&Asb[r][c4 * 4] = o;
        }
    } else {
        #pragma unroll
        for (int i = 0; i < 4; ++i) {
            int c = tid + i * 256;
            int r = c >> 4, o = c & 15;
            int grow = row0 + r;
            uint4 v = make_uint4(0, 0, 0, 0);
            if (grow < n) v = *(const uint4*)(Abf + (size_t)grow * 128 + o * 8);
            *(uint4*)&Asb[r][o * 8] = v;
        }
    }
    {
        const ushort* Wz = Wt + (size_t)(LAYER * 2 + z) * 16384;
        #pragma unroll
        for (int i = 0; i < 8; ++i) {
            int c = tid + i * 256;
            int r = c >> 4, o = c & 15;
            uint4 v = *(const uint4*)(Wz + r * 128 + o * 8);
            *(uint4*)&Wsb[r][o * 8] = v;
        }
    }
    if (z == 0) {
        int r = tid >> 4, o = tid & 15;
        uint4 v = *(const uint4*)(Watt + LAYER * 2048 + r * 128 + o * 8);
        *(uint4*)&Attb[r][o * 8] = v;
    }
    __syncthreads();

    const int w = tid >> 6, lane = tid & 63;
    const int wm = w >> 1, wn = w & 1;
    const int l15 = lane & 15, lg = lane >> 4;
    const bool doAtt = (z == 0) && (wn == 0);

    f32x4 acc[2][4];
    f32x4 accA[2];
    #pragma unroll
    for (int m = 0; m < 2; ++m) {
        accA[m] = (f32x4){0.f, 0.f, 0.f, 0.f};
        #pragma unroll
        for (int j = 0; j < 4; ++j)
            acc[m][j] = (f32x4){0.f, 0.f, 0.f, 0.f};
    }

    #pragma unroll
    for (int ks = 0; ks < 4; ++ks) {
        const int k0 = ks * 32 + 4 * lg;
        bf16x8 af[2], bfr[4];
        #pragma unroll
        for (int m = 0; m < 2; ++m) {
            const ushort* p = &Asb[wm * 32 + m * 16 + l15][k0];
            ushort4 lo = *(const ushort4*)p;
            ushort4 hi = *(const ushort4*)(p + 16);
            bf16x8 a;
            a[0] = (short)lo.x; a[1] = (short)lo.y; a[2] = (short)lo.z; a[3] = (short)lo.w;
            a[4] = (short)hi.x; a[5] = (short)hi.y; a[6] = (short)hi.z; a[7] = (short)hi.w;
            af[m] = a;
        }
        #pragma unroll
        for (int j = 0; j < 4; ++j) {
            const ushort* p = &Wsb[wn * 64 + j * 16 + l15][k0];
            ushort4 lo = *(const ushort4*)p;
            ushort4 hi = *(const ushort4*)(p + 16);
            bf16x8 b;
            b[0] = (short)lo.x; b[1] = (short)lo.y; b[2] = (short)lo.z; b[3] = (short)lo.w;
            b[4] = (short)hi.x; b[5] = (short)hi.y; b[6] = (short)hi.z; b[7] = (short)hi.w;
            bfr[j] = b;
        }
        #pragma unroll
        for (int m = 0; m < 2; ++m)
            #pragma unroll
            for (int j = 0; j < 4; ++j)
                acc[m][j] = __builtin_amdgcn_mfma_f32_16x16x32_bf16(
                    af[m], bfr[j], acc[m][j], 0, 0, 0);
        if (doAtt) {
            const ushort* p = &Attb[l15][k0];
            ushort4 lo = *(const ushort4*)p;
            ushort4 hi = *(const ushort4*)(p + 16);
            bf16x8 b;
            b[0] = (short)lo.x; b[1] = (short)lo.y; b[2] = (short)lo.z; b[3] = (short)lo.w;
            b[4] = (short)hi.x; b[5] = (short)hi.y; b[6] = (short)hi.z; b[7] = (short)hi.w;
            #pragma unroll
            for (int m = 0; m < 2; ++m)
                accA[m] = __builtin_amdgcn_mfma_f32_16x16x32_bf16(
                    af[m], b, accA[m], 0, 0, 0);
        }
    }

    if (doAtt && l15 < 8) {
        #pragma unroll
        for (int m = 0; m < 2; ++m)
            #pragma unroll
            for (int r = 0; r < 4; ++r) {
                int grow = row0 + wm * 32 + m * 16 + lg * 4 + r;
                if (grow < n) a_sd[(size_t)grow * 8 + l15] = accA[m][r];
            }
    }

    // ---- stage C in LDS (reuse Asb), then coalesced stores ----
    __syncthreads();
    ushort (*Cs)[136] = (ushort(*)[136])&Asb[0][0];
    #pragma unroll
    for (int m = 0; m < 2; ++m)
        #pragma unroll
        for (int j = 0; j < 4; ++j)
            #pragma unroll
            for (int r = 0; r < 4; ++r)
                Cs[wm * 32 + m * 16 + lg * 4 + r][wn * 64 + j * 16 + l15] =
                    f2bf(acc[m][j][r]);
    __syncthreads();
    #pragma unroll
    for (int i = 0; i < 4; ++i) {
        int u4 = tid + i * 256;           // 1024 uint4s = 64 rows x 16
        int r = u4 >> 4, c8 = u4 & 15;
        int grow = row0 + r;
        if (grow < n) {
            uint4 v = *(const uint4*)&Cs[r][c8 * 8];
            *(uint4*)(Cbf + (size_t)grow * 256 + z * 128 + c8 * 8) = v;
        }
    }
}

// ---------------------------------------------------------------------------
// Fused softmax + aggregate + epilogue. One wave per dst node.
// Shfl-free ADDRESS path: lane bits (j=lane>>4, a=(lane>>2)&3, b=lane&3).
// Each lane loads its own 4 edge indices srcSorted[t+j+4m] (L1 broadcast) and
// issues 4 row-gathers immediately. Its exp edge is e=j+4b (src index already
// in register s[b]); head a. ee shfl happens on the multiply side only,
// overlapped with gather latency. den: xor{1,2,16,32} -> den[head a];
// lanes 0-15 have a == g>>2, matching their channel head.
// MODE 0: +skip+b+bl -> LayerNorm -> ReLU -> hbf (bf16)
// MODE 1: +skip+b+bl -> out (fp32)
// ---------------------------------------------------------------------------
template <int MODE>
__global__ __launch_bounds__(256) void aggregate_fused_kernel(
    const ushort* __restrict__ srcSorted, const int* __restrict__ offs,
    const ushort* __restrict__ degs,
    const ushort* __restrict__ bufbf,   // [n][256] xs|skip (bf16)
    const float* __restrict__ a_sd,     // [n][8]: 0-3 a_s, 4-7 a_d
    const float* __restrict__ bias_a, const float* __restrict__ bias_l,
    const float* __restrict__ gamma, const float* __restrict__ beta,
    ushort* __restrict__ hbf, float* __restrict__ out, int n)
{
    int node = (blockIdx.x * blockDim.x + threadIdx.x) >> 6;
    int lane = threadIdx.x & 63;
    if (node >= n) return;
    int beg = offs[node];
    int end = beg + degs[node];
    const int j = lane >> 4;            // gather slot / edge low bits
    const int g = lane & 15;            // channel group (8 ch)
    const int a = (lane >> 2) & 3;      // exp head
    const int b = lane & 3;             // exp edge high bits (edge = j+4b)
    const int h = g >> 2;               // head of my channels

    float ada = a_sd[(size_t)node * 8 + 4 + a];

    float acc[8] = {};
    float denp = 0.f;

    for (int t = beg; t < end; t += 16) {
        // direct index loads (no shfl in address path)
        int i0 = t + j;
        int i1 = t + j + 4;
        int i2 = t + j + 8;
        int i3 = t + j + 12;
        int s0 = srcSorted[(i0 < end) ? i0 : (end - 1)];
        int s1 = srcSorted[(i1 < end) ? i1 : (end - 1)];
        int s2 = srcSorted[(i2 < end) ? i2 : (end - 1)];
        int s3 = srcSorted[(i3 < end) ? i3 : (end - 1)];
        // issue all 4 gathers now
        uint4 x0 = *(const uint4*)(bufbf + (size_t)s0 * 256 + g * 8);
        uint4 x1 = *(const uint4*)(bufbf + (size_t)s1 * 256 + g * 8);
        uint4 x2 = *(const uint4*)(bufbf + (size_t)s2 * 256 + g * 8);
        uint4 x3 = *(const uint4*)(bufbf + (size_t)s3 * 256 + g * 8);
        // exp for my (edge j+4b, head a) — src index already in registers
        int se = (b == 0) ? s0 : (b == 1) ? s1 : (b == 2) ? s2 : s3;
        int ie = t + j + 4 * b;
        float as = a_sd[(size_t)se * 8 + a];
        float e = as + ada;
        e = (e > 0.f) ? e : LRELU * e;
        float ee = (ie < end) ? __expf(e) : 0.f;
        denp += ee;
        // distribute ee: edge j+4m / head h lives at lane 16*j + 4*h + m
        float ee0 = __shfl(ee, 16 * j + 4 * h + 0);
        float ee1 = __shfl(ee, 16 * j + 4 * h + 1);
        float ee2 = __shfl(ee, 16 * j + 4 * h + 2);
        float ee3 = __shfl(ee, 16 * j + 4 * h + 3);
        acc[0] = fmaf(ee0, bflo(x0.x), acc[0]);
        acc[1] = fmaf(ee0, bfhi(x0.x), acc[1]);
        acc[2] = fmaf(ee0, bflo(x0.y), acc[2]);
        acc[3] = fmaf(ee0, bfhi(x0.y), acc[3]);
        acc[4] = fmaf(ee0, bflo(x0.z), acc[4]);
        acc[5] = fmaf(ee0, bfhi(x0.z), acc[5]);
        acc[6] = fmaf(ee0, bflo(x0.w), acc[6]);
        acc[7] = fmaf(ee0, bfhi(x0.w), acc[7]);
        acc[0] = fmaf(ee1, bflo(x1.x), acc[0]);
        acc[1] = fmaf(ee1, bfhi(x1.x), acc[1]);
        acc[2] = fmaf(ee1, bflo(x1.y), acc[2]);
        acc[3] = fmaf(ee1, bfhi(x1.y), acc[3]);
        acc[4] = fmaf(ee1, bflo(x1.z), acc[4]);
        acc[5] = fmaf(ee1, bfhi(x1.z), acc[5]);
        acc[6] = fmaf(ee1, bflo(x1.w), acc[6]);
        acc[7] = fmaf(ee1, bfhi(x1.w), acc[7]);
        acc[0] = fmaf(ee2, bflo(x2.x), acc[0]);
        acc[1] = fmaf(ee2, bfhi(x2.x), acc[1]);
        acc[2] = fmaf(ee2, bflo(x2.y), acc[2]);
        acc[3] = fmaf(ee2, bfhi(x2.y), acc[3]);
        acc[4] = fmaf(ee2, bflo(x2.z), acc[4]);
        acc[5] = fmaf(ee2, bfhi(x2.z), acc[5]);
        acc[6] = fmaf(ee2, bflo(x2.w), acc[6]);
        acc[7] = fmaf(ee2, bfhi(x2.w), acc[7]);
        acc[0] = fmaf(ee3, bflo(x3.x), acc[0]);
        acc[1] = fmaf(ee3, bfhi(x3.x), acc[1]);
        acc[2] = fmaf(ee3, bflo(x3.y), acc[2]);
        acc[3] = fmaf(ee3, bfhi(x3.y), acc[3]);
        acc[4] = fmaf(ee3, bflo(x3.z), acc[4]);
        acc[5] = fmaf(ee3, bfhi(x3.z), acc[5]);
        acc[6] = fmaf(ee3, bflo(x3.w), acc[6]);
        acc[7] = fmaf(ee3, bfhi(x3.w), acc[7]);
    }

    // reduce acc over gather slots (lane bits 4,5)
    #pragma unroll
    for (int c = 0; c < 8; ++c) {
        acc[c] += __shfl_xor(acc[c], 16);
        acc[c] += __shfl_xor(acc[c], 32);
    }
    // reduce den over edge bits (b: bits 0-1, j: bits 4-5) -> den[head a]
    denp += __shfl_xor(denp, 1);
    denp += __shfl_xor(denp, 2);
    denp += __shfl_xor(denp, 16);
    denp += __shfl_xor(denp, 32);
    // lanes 0-15: a == g>>2 already matches the channel head
    float den = denp;

    if (lane < 16) {
        float inv = 1.f / (den + 1e-16f);
        uint4 sk = *(const uint4*)(bufbf + (size_t)node * 256 + 128 + g * 8);
        float4 ba0 = *(const float4*)(bias_a + g * 8);
        float4 ba1 = *(const float4*)(bias_a + g * 8 + 4);
        float4 bl0 = *(const float4*)(bias_l + g * 8);
        float4 bl1 = *(const float4*)(bias_l + g * 8 + 4);
        float v[8];
        v[0] = acc[0] * inv + bflo(sk.x) + ba0.x + bl0.x;
        v[1] = acc[1] * inv + bfhi(sk.x) + ba0.y + bl0.y;
        v[2] = acc[2] * inv + bflo(sk.y) + ba0.z + bl0.z;
        v[3] = acc[3] * inv + bfhi(sk.y) + ba0.w + bl0.w;
        v[4] = acc[4] * inv + bflo(sk.z) + ba1.x + bl1.x;
        v[5] = acc[5] * inv + bfhi(sk.z) + ba1.y + bl1.y;
        v[6] = acc[6] * inv + bflo(sk.w) + ba1.z + bl1.z;
        v[7] = acc[7] * inv + bfhi(sk.w) + ba1.w + bl1.w;

        if (MODE == 0) {
            float sum = 0.f, sq = 0.f;
            #pragma unroll
            for (int c = 0; c < 8; ++c) { sum += v[c]; sq += v[c] * v[c]; }
            #pragma unroll
            for (int off = 1; off < 16; off <<= 1) {
                sum += __shfl_xor(sum, off);
                sq  += __shfl_xor(sq, off);
            }
            float mu = sum * (1.f / 128.f);
            float var = sq * (1.f / 128.f) - mu * mu;
            float rs = rsqrtf(var + LN_EPS);
            float4 gm0 = *(const float4*)(gamma + g * 8);
            float4 gm1 = *(const float4*)(gamma + g * 8 + 4);
            float4 bt0 = *(const float4*)(beta + g * 8);
            float4 bt1 = *(const float4*)(beta + g * 8 + 4);
            float o[8];
            o[0] = fmaxf((v[0] - mu) * rs * gm0.x + bt0.x, 0.f);
            o[1] = fmaxf((v[1] - mu) * rs * gm0.y + bt0.y, 0.f);
            o[2] = fmaxf((v[2] - mu) * rs * gm0.z + bt0.z, 0.f);
            o[3] = fmaxf((v[3] - mu) * rs * gm0.w + bt0.w, 0.f);
            o[4] = fmaxf((v[4] - mu) * rs * gm1.x + bt1.x, 0.f);
            o[5] = fmaxf((v[5] - mu) * rs * gm1.y + bt1.y, 0.f);
            o[6] = fmaxf((v[6] - mu) * rs * gm1.z + bt1.z, 0.f);
            o[7] = fmaxf((v[7] - mu) * rs * gm1.w + bt1.w, 0.f);
            uint4 st;
            st.x = (uint)f2bf(o[0]) | ((uint)f2bf(o[1]) << 16);
            st.y = (uint)f2bf(o[2]) | ((uint)f2bf(o[3]) << 16);
            st.z = (uint)f2bf(o[4]) | ((uint)f2bf(o[5]) << 16);
            st.w = (uint)f2bf(o[6]) | ((uint)f2bf(o[7]) << 16);
            *(uint4*)(hbf + (size_t)node * 128 + g * 8) = st;
        } else {
            *(float4*)(out + (size_t)node * 128 + g * 8) =
                make_float4(v[0], v[1], v[2], v[3]);
            *(float4*)(out + (size_t)node * 128 + g * 8 + 4) =
                make_float4(v[4], v[5], v[6], v[7]);
        }
    }
}

extern "C" void kernel_launch(void* const* d_in, const int* in_sizes, int n_in,
                              void* d_out, int out_size, void* d_ws, size_t ws_size,
                              hipStream_t stream) {
    const float* x       = (const float*)d_in[0];
    const int*   ei      = (const int*)d_in[1];
    const int*   src     = ei;
    const int*   dst     = ei + E_EDGES;
    const float* W1_src  = (const float*)d_in[2];
    const float* W1_dst  = (const float*)d_in[3];
    const float* att1_s  = (const float*)d_in[4];
    const float* att1_d  = (const float*)d_in[5];
    const float* b1      = (const float*)d_in[6];
    const float* Wl1     = (const float*)d_in[7];
    const float* bl1     = (const float*)d_in[8];
    const float* gamma   = (const float*)d_in[9];
    const float* beta    = (const float*)d_in[10];
    const float* W2_src  = (const float*)d_in[11];
    const float* W2_dst  = (const float*)d_in[12];
    const float* att2_s  = (const float*)d_in[13];
    const float* att2_d  = (const float*)d_in[14];
    const float* b2      = (const float*)d_in[15];
    const float* Wl2     = (const float*)d_in[16];
    const float* bl2     = (const float*)d_in[17];
    float* out = (float*)d_out;

    // workspace layout
    char* p = (char*)d_ws;
    float* a_sd        = (float*)p;      p += (size_t)N_NODES * 8 * 4;
    int* offs          = (int*)p;        p += (size_t)N_NODES * 4;
    int* bucketCursor  = (int*)p;        p += 256 * 4;
    uint* pairs        = (uint*)p;       p += (size_t)NBUCK * BCAP * 4;
    ushort* degs       = (ushort*)p;     p += (size_t)N_NODES * 2;
    ushort* hbf        = (ushort*)p;     p += (size_t)N_NODES * 128 * 2;
    ushort* bufbf      = (ushort*)p;     p += (size_t)N_NODES * 256 * 2;
    ushort* Wt         = (ushort*)p;     p += (size_t)4 * 16384 * 2;
    ushort* Watt       = (ushort*)p;     p += (size_t)2 * 2048 * 2;
    ushort* srcSorted  = (ushort*)p;     p += (size_t)NBUCK * BCAP * 2;

    dim3 ggrid(2, (N_NODES + 63) / 64);
    int edge_blocks = (E_EDGES + 4095) / 4096;   // 196
    int wave_grid   = (N_NODES + 3) / 4;

    // -------- prep (weights + cursor zero), then CSR build --------
    prep_all_kernel<<<259, 256, 0, stream>>>(
        W1_src, Wl1, W1_dst, att1_s, att1_d,
        W2_src, Wl2, W2_dst, att2_s, att2_d, Wt, Watt, bucketCursor);
    bucket_scatter_kernel<<<edge_blocks, 256, 0, stream>>>(src, dst, bucketCursor, pairs, E_EDGES);
    bucket_sort_kernel<<<NBUCK, 256, 0, stream>>>(pairs, bucketCursor, offs, degs, srcSorted, N_NODES);

    // -------- layer 1 --------
    gemm_fused_kernel<0><<<ggrid, 256, 0, stream>>>(x, nullptr, Wt, Watt, bufbf, a_sd, N_NODES);
    aggregate_fused_kernel<0><<<wave_grid, 256, 0, stream>>>(
        srcSorted, offs, degs, bufbf, a_sd, b1, bl1, gamma, beta, hbf, nullptr, N_NODES);

    // -------- layer 2 --------
    gemm_fused_kernel<1><<<ggrid, 256, 0, stream>>>(nullptr, hbf, Wt, Watt, bufbf, a_sd, N_NODES);
    aggregate_fused_kernel<1><<<wave_grid, 256, 0, stream>>>(
        srcSorted, offs, degs, bufbf, a_sd, b2, bl2, nullptr, nullptr, nullptr, out, N_NODES);
}

// Round 13
// 274.190 us; speedup vs baseline: 1.1874x; 1.0300x over previous
//
#include <hip/hip_runtime.h>

#define N_NODES 50000
#define E_EDGES 800000
#define LRELU 0.2f
#define LN_EPS 1e-5f
#define NBUCK 196             // ceil(50000/256)
#define BSHIFT 8              // 256 nodes per bucket
#define BCAP 4608             // per-bucket capacity (mean 4096, sigma 64)

typedef short bf16x8 __attribute__((ext_vector_type(8)));
typedef float f32x4 __attribute__((ext_vector_type(4)));

__device__ __forceinline__ ushort f2bf(float f) {
    uint u = __float_as_uint(f);
    u += 0x7FFF + ((u >> 16) & 1);          // RNE
    return (ushort)(u >> 16);
}
__device__ __forceinline__ float bflo(uint u) { return __uint_as_float(u << 16); }
__device__ __forceinline__ float bfhi(uint u) { return __uint_as_float(u & 0xFFFF0000u); }

// fragment-order offset for a 16(row)x128(k) tile block:
// [ks(4)][lg(4)][r15(16)][8], elem = half*4+t where k = ks*32 + half*16 + lg*4 + t
__device__ __forceinline__ int fragoff16(int r15, int k) {
    int ks = k >> 5, half = (k >> 4) & 1, lg = (k & 15) >> 2, t = k & 3;
    return (((ks * 4 + lg) * 16) + r15) * 8 + half * 4 + t;
}

// ---------------------------------------------------------------------------
// CSR stage 1: grouped scatter into fixed-capacity bucket regions.
// ---------------------------------------------------------------------------
__global__ __launch_bounds__(256) void bucket_scatter_kernel(
    const int* __restrict__ src, const int* __restrict__ dst,
    int* __restrict__ bucketCursor, uint* __restrict__ pairs, int e)
{
    __shared__ int lhist[256];
    __shared__ int lscan[NBUCK];
    __shared__ int lcur[NBUCK];
    __shared__ int lbase[NBUCK];
    __shared__ int wsum[4];
    __shared__ uint stageW[4096];
    __shared__ int  stageA[4096];
    int t = threadIdx.x;
    int e0 = blockIdx.x * 4096;
    int count = min(4096, e - e0);

    lhist[t] = 0;
    if (t < NBUCK) lcur[t] = 0;
    __syncthreads();

    int  bb[16];
    uint pk[16];
    #pragma unroll
    for (int q = 0; q < 16; ++q) {
        int li = t + q * 256;
        if (li < count) {
            int d = dst[e0 + li];
            int s = src[e0 + li];
            bb[q] = d >> BSHIFT;
            pk[q] = (uint)s | ((uint)(d & 255) << 16);
            atomicAdd(&lhist[bb[q]], 1);
        } else bb[q] = -1;
    }
    __syncthreads();

    int orig = lhist[t];
    int lane64 = t & 63, wv = t >> 6;
    int incl = orig;
    #pragma unroll
    for (int off = 1; off < 64; off <<= 1) {
        int u = __shfl_up(incl, off);
        if (lane64 >= off) incl += u;
    }
    if (lane64 == 63) wsum[wv] = incl;
    __syncthreads();
    if (wv > 0) incl += wsum[0];
    if (wv > 1) incl += wsum[1];
    if (wv > 2) incl += wsum[2];
    if (t < NBUCK) {
        lscan[t] = incl - orig;                           // exclusive
        lbase[t] = t * BCAP + (orig ? atomicAdd(&bucketCursor[t], orig) : 0);
    }
    __syncthreads();

    #pragma unroll
    for (int q = 0; q < 16; ++q) {
        if (bb[q] >= 0) {
            int slot = lscan[bb[q]] + atomicAdd(&lcur[bb[q]], 1);
            stageW[slot] = pk[q];
            stageA[slot] = lbase[bb[q]] + (slot - lscan[bb[q]]);
        }
    }
    __syncthreads();

    #pragma unroll
    for (int q = 0; q < 16; ++q) {
        int li = t + q * 256;
        if (li < count) pairs[stageA[li]] = stageW[li];
    }
}

// ---------------------------------------------------------------------------
// CSR stage 2: per-bucket sort -> offs/degs/srcSorted.
// ---------------------------------------------------------------------------
__global__ __launch_bounds__(256) void bucket_sort_kernel(
    const uint* __restrict__ pairs, const int* __restrict__ bucketCursor,
    int* __restrict__ offs, ushort* __restrict__ degs,
    ushort* __restrict__ srcSorted, int n)
{
    __shared__ int cnt[256], cur[256];
    __shared__ int wsum[4];
    int b = blockIdx.x, t = threadIdx.x;
    int base = b * BCAP;
    int m = bucketCursor[b];
    cnt[t] = 0; cur[t] = 0;
    __syncthreads();
    for (int i = t; i < m; i += 256)
        atomicAdd(&cnt[pairs[base + i] >> 16], 1);
    __syncthreads();

    int orig = cnt[t];
    int lane64 = t & 63, wv = t >> 6;
    int incl = orig;
    #pragma unroll
    for (int off = 1; off < 64; off <<= 1) {
        int u = __shfl_up(incl, off);
        if (lane64 >= off) incl += u;
    }
    if (lane64 == 63) wsum[wv] = incl;
    __syncthreads();
    if (wv > 0) incl += wsum[0];
    if (wv > 1) incl += wsum[1];
    if (wv > 2) incl += wsum[2];
    int excl = incl - orig;

    int node = (b << BSHIFT) + t;
    if (node < n) {
        offs[node] = base + excl;
        degs[node] = (ushort)orig;
    }
    cnt[t] = excl;
    __syncthreads();
    for (int i = t; i < m; i += 256) {
        uint w = pairs[base + i];
        int dl = w >> 16;
        int pos = cnt[dl] + atomicAdd(&cur[dl], 1);
        srcSorted[base + pos] = (ushort)(w & 0xFFFFu);
    }
}

// ---------------------------------------------------------------------------
// Weight prep for BOTH layers (FRAGMENT-ORDERED Wt/Watt) + cursor zeroing.
// Wt layout: [lw][ntile(8)][ks(4)][lg(4)][n15(16)][8] per 16384-elem matrix.
// Watt layout per layer: [ks(4)][lg(4)][c(16)][8]  (c<8 meaningful, else 0).
// ---------------------------------------------------------------------------
__global__ __launch_bounds__(256) void prep_all_kernel(
    const float* __restrict__ W1s, const float* __restrict__ Wl1,
    const float* __restrict__ W1d, const float* __restrict__ a1s,
    const float* __restrict__ a1d,
    const float* __restrict__ W2s, const float* __restrict__ Wl2,
    const float* __restrict__ W2d, const float* __restrict__ a2s,
    const float* __restrict__ a2d,
    ushort* __restrict__ Wt, ushort* __restrict__ Watt,
    int* __restrict__ bucketCursor)
{
    int t = threadIdx.x;
    if (blockIdx.x < 256) {
        int idx = blockIdx.x * 256 + t;          // [0,65536)
        int lw = idx >> 14, rem = idx & 16383;
        int nn = rem >> 7, k = rem & 127;
        const float* W = (lw == 0) ? W1s : (lw == 1) ? Wl1 : (lw == 2) ? W2s : Wl2;
        int off = ((nn >> 4) * 2048) + fragoff16(nn & 15, k);
        Wt[lw * 16384 + off] = f2bf(W[k * 128 + nn]);
    } else if (blockIdx.x < 258) {
        int L = blockIdx.x - 256;
        const float* Ws = L ? W2s : W1s;
        const float* Wd = L ? W2d : W1d;
        const float* as = L ? a2s : a1s;
        const float* adv = L ? a2d : a1d;
        #pragma unroll
        for (int q = 0; q < 8; ++q) {
            int e = q * 256 + t;                 // [0,2048)
            int c = e >> 7, f = e & 127;
            float v = 0.f;
            if (c < 8) {
                const float* W  = (c < 4) ? Ws : Wd;
                const float* av = (c < 4) ? as : adv;
                int h = c & 3;
                #pragma unroll
                for (int j = 0; j < 32; ++j)
                    v += W[f * 128 + h * 32 + j] * av[h * 32 + j];
            }
            Watt[L * 2048 + fragoff16(c, f)] = f2bf(v);
        }
    } else {
        if (t < NBUCK) bucketCursor[t] = 0;
    }
}

// ---------------------------------------------------------------------------
// MFMA GEMM + fused attention-score tile. FRAGMENT-ORDERED LDS:
// frag load = ONE ds_read_b128, zero repacking VALU.
// Af: [mtile(4)][ks(4)][lg(4)][r15(16)][8] = 16KB (A swizzled on LDS write)
// Wf: linear copy of frag-ordered Wt (32KB); Attf: 4KB.
// C staged in Wf (padded [64][136]) for coalesced stores.
// ---------------------------------------------------------------------------
template <int LAYER>
__global__ __launch_bounds__(256) void gemm_fused_kernel(
    const float* __restrict__ Afp, const ushort* __restrict__ Abf,
    const ushort* __restrict__ Wt, const ushort* __restrict__ Watt,
    ushort* __restrict__ Cbf, float* __restrict__ a_sd, int n)
{
    __shared__ ushort Af[64 * 128];     // 16KB frag-ordered A
    __shared__ ushort Wf[128 * 128];    // 32KB frag-ordered W (linear copy)
    __shared__ ushort Attf[2048];       // 4KB frag-ordered att
    const int z = blockIdx.x;
    const int row0 = blockIdx.y * 64;
    const int tid = threadIdx.x;

    if (LAYER == 0) {
        // fp32 x: float4 = 4 consecutive k (same ks/half/lg, t=0..3) -> one 8B write
        #pragma unroll
        for (int i = 0; i < 8; ++i) {
            int idx = tid + i * 256;
            int r = idx >> 5, c4 = idx & 31;
            int k0 = c4 * 4;
            int grow = row0 + r;
            float4 v = make_float4(0.f, 0.f, 0.f, 0.f);
            if (grow < n) v = *(const float4*)(Afp + (size_t)grow * 128 + k0);
            ushort4 o;
            o.x = f2bf(v.x); o.y = f2bf(v.y); o.z = f2bf(v.z); o.w = f2bf(v.w);
            int ks = k0 >> 5, half = (k0 >> 4) & 1, lg = (k0 & 15) >> 2;
            int off = ((((r >> 4) * 4 + ks) * 4 + lg) * 16 + (r & 15)) * 8 + half * 4;
            *(ushort4*)&Af[off] = o;
        }
    } else {
        // bf16: uint4 = 8 consecutive k -> two 8B writes (lg and lg+1)
        #pragma unroll
        for (int i = 0; i < 4; ++i) {
            int c = tid + i * 256;
            int r = c >> 4, o = c & 15;
            int k0 = o * 8;
            int grow = row0 + r;
            uint4 v = make_uint4(0, 0, 0, 0);
            if (grow < n) v = *(const uint4*)(Abf + (size_t)grow * 128 + k0);
            int ks = k0 >> 5, half = (k0 >> 4) & 1, lgA = (k0 & 15) >> 2;
            int base = (((r >> 4) * 4 + ks) * 4) * 16 * 8 + (r & 15) * 8 + half * 4;
            *(uint2*)&Af[base + lgA * 128]       = make_uint2(v.x, v.y);
            *(uint2*)&Af[base + (lgA + 1) * 128] = make_uint2(v.z, v.w);
        }
    }
    {
        // W: straight linear copy (already frag-ordered in global)
        const ushort* Wz = Wt + (size_t)(LAYER * 2 + z) * 16384;
        #pragma unroll
        for (int i = 0; i < 8; ++i) {
            int u4 = tid + i * 256;
            *(uint4*)&Wf[u4 * 8] = *(const uint4*)(Wz + u4 * 8);
        }
    }
    if (z == 0) {
        *(uint4*)&Attf[tid * 8] = *(const uint4*)(Watt + LAYER * 2048 + tid * 8);
    }
    __syncthreads();

    const int w = tid >> 6, lane = tid & 63;
    const int wm = w >> 1, wn = w & 1;
    const int l15 = lane & 15, lg = lane >> 4;
    const bool doAtt = (z == 0) && (wn == 0);

    f32x4 acc[2][4];
    f32x4 accA[2];
    #pragma unroll
    for (int m = 0; m < 2; ++m) {
        accA[m] = (f32x4){0.f, 0.f, 0.f, 0.f};
        #pragma unroll
        for (int j = 0; j < 4; ++j)
            acc[m][j] = (f32x4){0.f, 0.f, 0.f, 0.f};
    }

    #pragma unroll
    for (int ks = 0; ks < 4; ++ks) {
        bf16x8 af[2], bfr[4];
        #pragma unroll
        for (int m = 0; m < 2; ++m)
            af[m] = *(const bf16x8*)&Af[((((wm * 2 + m) * 4 + ks) * 4 + lg) * 16 + l15) * 8];
        #pragma unroll
        for (int j = 0; j < 4; ++j)
            bfr[j] = *(const bf16x8*)&Wf[((((wn * 4 + j) * 4 + ks) * 4 + lg) * 16 + l15) * 8];
        #pragma unroll
        for (int m = 0; m < 2; ++m)
            #pragma unroll
            for (int j = 0; j < 4; ++j)
                acc[m][j] = __builtin_amdgcn_mfma_f32_16x16x32_bf16(
                    af[m], bfr[j], acc[m][j], 0, 0, 0);
        if (doAtt) {
            bf16x8 b = *(const bf16x8*)&Attf[((ks * 4 + lg) * 16 + l15) * 8];
            #pragma unroll
            for (int m = 0; m < 2; ++m)
                accA[m] = __builtin_amdgcn_mfma_f32_16x16x32_bf16(
                    af[m], b, accA[m], 0, 0, 0);
        }
    }

    if (doAtt && l15 < 8) {
        #pragma unroll
        for (int m = 0; m < 2; ++m)
            #pragma unroll
            for (int r = 0; r < 4; ++r) {
                int grow = row0 + wm * 32 + m * 16 + lg * 4 + r;
                if (grow < n) a_sd[(size_t)grow * 8 + l15] = accA[m][r];
            }
    }

    // ---- stage C in Wf (padded), then coalesced stores ----
    __syncthreads();
    ushort (*Cs)[136] = (ushort(*)[136])&Wf[0];
    #pragma unroll
    for (int m = 0; m < 2; ++m)
        #pragma unroll
        for (int j = 0; j < 4; ++j)
            #pragma unroll
            for (int r = 0; r < 4; ++r)
                Cs[wm * 32 + m * 16 + lg * 4 + r][wn * 64 + j * 16 + l15] =
                    f2bf(acc[m][j][r]);
    __syncthreads();
    #pragma unroll
    for (int i = 0; i < 4; ++i) {
        int u4 = tid + i * 256;           // 1024 uint4s = 64 rows x 16
        int r = u4 >> 4, c8 = u4 & 15;
        int grow = row0 + r;
        if (grow < n) {
            uint4 v = *(const uint4*)&Cs[r][c8 * 8];
            *(uint4*)(Cbf + (size_t)grow * 256 + z * 128 + c8 * 8) = v;
        }
    }
}

// ---------------------------------------------------------------------------
// Fused softmax + aggregate + epilogue (unchanged from R11 — at plateau).
// ---------------------------------------------------------------------------
template <int MODE>
__global__ __launch_bounds__(256) void aggregate_fused_kernel(
    const ushort* __restrict__ srcSorted, const int* __restrict__ offs,
    const ushort* __restrict__ degs,
    const ushort* __restrict__ bufbf,   // [n][256] xs|skip (bf16)
    const float* __restrict__ a_sd,     // [n][8]: 0-3 a_s, 4-7 a_d
    const float* __restrict__ bias_a, const float* __restrict__ bias_l,
    const float* __restrict__ gamma, const float* __restrict__ beta,
    ushort* __restrict__ hbf, float* __restrict__ out, int n)
{
    int node = (blockIdx.x * blockDim.x + threadIdx.x) >> 6;
    int lane = threadIdx.x & 63;
    if (node >= n) return;
    int beg = offs[node];
    int end = beg + degs[node];
    const int j = lane >> 4;            // gather slot / edge low bits
    const int g = lane & 15;            // channel group (8 ch)
    const int a = (lane >> 2) & 3;      // exp head
    const int b = lane & 3;             // exp edge high bits (edge = j+4b)
    const int h = g >> 2;               // head of my channels

    float ada = a_sd[(size_t)node * 8 + 4 + a];

    float acc[8] = {};
    float denp = 0.f;

    for (int t = beg; t < end; t += 16) {
        int i0 = t + j;
        int i1 = t + j + 4;
        int i2 = t + j + 8;
        int i3 = t + j + 12;
        int s0 = srcSorted[(i0 < end) ? i0 : (end - 1)];
        int s1 = srcSorted[(i1 < end) ? i1 : (end - 1)];
        int s2 = srcSorted[(i2 < end) ? i2 : (end - 1)];
        int s3 = srcSorted[(i3 < end) ? i3 : (end - 1)];
        uint4 x0 = *(const uint4*)(bufbf + (size_t)s0 * 256 + g * 8);
        uint4 x1 = *(const uint4*)(bufbf + (size_t)s1 * 256 + g * 8);
        uint4 x2 = *(const uint4*)(bufbf + (size_t)s2 * 256 + g * 8);
        uint4 x3 = *(const uint4*)(bufbf + (size_t)s3 * 256 + g * 8);
        int se = (b == 0) ? s0 : (b == 1) ? s1 : (b == 2) ? s2 : s3;
        int ie = t + j + 4 * b;
        float as = a_sd[(size_t)se * 8 + a];
        float e = as + ada;
        e = (e > 0.f) ? e : LRELU * e;
        float ee = (ie < end) ? __expf(e) : 0.f;
        denp += ee;
        float ee0 = __shfl(ee, 16 * j + 4 * h + 0);
        float ee1 = __shfl(ee, 16 * j + 4 * h + 1);
        float ee2 = __shfl(ee, 16 * j + 4 * h + 2);
        float ee3 = __shfl(ee, 16 * j + 4 * h + 3);
        acc[0] = fmaf(ee0, bflo(x0.x), acc[0]);
        acc[1] = fmaf(ee0, bfhi(x0.x), acc[1]);
        acc[2] = fmaf(ee0, bflo(x0.y), acc[2]);
        acc[3] = fmaf(ee0, bfhi(x0.y), acc[3]);
        acc[4] = fmaf(ee0, bflo(x0.z), acc[4]);
        acc[5] = fmaf(ee0, bfhi(x0.z), acc[5]);
        acc[6] = fmaf(ee0, bflo(x0.w), acc[6]);
        acc[7] = fmaf(ee0, bfhi(x0.w), acc[7]);
        acc[0] = fmaf(ee1, bflo(x1.x), acc[0]);
        acc[1] = fmaf(ee1, bfhi(x1.x), acc[1]);
        acc[2] = fmaf(ee1, bflo(x1.y), acc[2]);
        acc[3] = fmaf(ee1, bfhi(x1.y), acc[3]);
        acc[4] = fmaf(ee1, bflo(x1.z), acc[4]);
        acc[5] = fmaf(ee1, bfhi(x1.z), acc[5]);
        acc[6] = fmaf(ee1, bflo(x1.w), acc[6]);
        acc[7] = fmaf(ee1, bfhi(x1.w), acc[7]);
        acc[0] = fmaf(ee2, bflo(x2.x), acc[0]);
        acc[1] = fmaf(ee2, bfhi(x2.x), acc[1]);
        acc[2] = fmaf(ee2, bflo(x2.y), acc[2]);
        acc[3] = fmaf(ee2, bfhi(x2.y), acc[3]);
        acc[4] = fmaf(ee2, bflo(x2.z), acc[4]);
        acc[5] = fmaf(ee2, bfhi(x2.z), acc[5]);
        acc[6] = fmaf(ee2, bflo(x2.w), acc[6]);
        acc[7] = fmaf(ee2, bfhi(x2.w), acc[7]);
        acc[0] = fmaf(ee3, bflo(x3.x), acc[0]);
        acc[1] = fmaf(ee3, bfhi(x3.x), acc[1]);
        acc[2] = fmaf(ee3, bflo(x3.y), acc[2]);
        acc[3] = fmaf(ee3, bfhi(x3.y), acc[3]);
        acc[4] = fmaf(ee3, bflo(x3.z), acc[4]);
        acc[5] = fmaf(ee3, bfhi(x3.z), acc[5]);
        acc[6] = fmaf(ee3, bflo(x3.w), acc[6]);
        acc[7] = fmaf(ee3, bfhi(x3.w), acc[7]);
    }

    #pragma unroll
    for (int c = 0; c < 8; ++c) {
        acc[c] += __shfl_xor(acc[c], 16);
        acc[c] += __shfl_xor(acc[c], 32);
    }
    denp += __shfl_xor(denp, 1);
    denp += __shfl_xor(denp, 2);
    denp += __shfl_xor(denp, 16);
    denp += __shfl_xor(denp, 32);
    float den = denp;

    if (lane < 16) {
        float inv = 1.f / (den + 1e-16f);
        uint4 sk = *(const uint4*)(bufbf + (size_t)node * 256 + 128 + g * 8);
        float4 ba0 = *(const float4*)(bias_a + g * 8);
        float4 ba1 = *(const float4*)(bias_a + g * 8 + 4);
        float4 bl0 = *(const float4*)(bias_l + g * 8);
        float4 bl1 = *(const float4*)(bias_l + g * 8 + 4);
        float v[8];
        v[0] = acc[0] * inv + bflo(sk.x) + ba0.x + bl0.x;
        v[1] = acc[1] * inv + bfhi(sk.x) + ba0.y + bl0.y;
        v[2] = acc[2] * inv + bflo(sk.y) + ba0.z + bl0.z;
        v[3] = acc[3] * inv + bfhi(sk.y) + ba0.w + bl0.w;
        v[4] = acc[4] * inv + bflo(sk.z) + ba1.x + bl1.x;
        v[5] = acc[5] * inv + bfhi(sk.z) + ba1.y + bl1.y;
        v[6] = acc[6] * inv + bflo(sk.w) + ba1.z + bl1.z;
        v[7] = acc[7] * inv + bfhi(sk.w) + ba1.w + bl1.w;

        if (MODE == 0) {
            float sum = 0.f, sq = 0.f;
            #pragma unroll
            for (int c = 0; c < 8; ++c) { sum += v[c]; sq += v[c] * v[c]; }
            #pragma unroll
            for (int off = 1; off < 16; off <<= 1) {
                sum += __shfl_xor(sum, off);
                sq  += __shfl_xor(sq, off);
            }
            float mu = sum * (1.f / 128.f);
            float var = sq * (1.f / 128.f) - mu * mu;
            float rs = rsqrtf(var + LN_EPS);
            float4 gm0 = *(const float4*)(gamma + g * 8);
            float4 gm1 = *(const float4*)(gamma + g * 8 + 4);
            float4 bt0 = *(const float4*)(beta + g * 8);
            float4 bt1 = *(const float4*)(beta + g * 8 + 4);
            float o[8];
            o[0] = fmaxf((v[0] - mu) * rs * gm0.x + bt0.x, 0.f);
            o[1] = fmaxf((v[1] - mu) * rs * gm0.y + bt0.y, 0.f);
            o[2] = fmaxf((v[2] - mu) * rs * gm0.z + bt0.z, 0.f);
            o[3] = fmaxf((v[3] - mu) * rs * gm0.w + bt0.w, 0.f);
            o[4] = fmaxf((v[4] - mu) * rs * gm1.x + bt1.x, 0.f);
            o[5] = fmaxf((v[5] - mu) * rs * gm1.y + bt1.y, 0.f);
            o[6] = fmaxf((v[6] - mu) * rs * gm1.z + bt1.z, 0.f);
            o[7] = fmaxf((v[7] - mu) * rs * gm1.w + bt1.w, 0.f);
            uint4 st;
            st.x = (uint)f2bf(o[0]) | ((uint)f2bf(o[1]) << 16);
            st.y = (uint)f2bf(o[2]) | ((uint)f2bf(o[3]) << 16);
            st.z = (uint)f2bf(o[4]) | ((uint)f2bf(o[5]) << 16);
            st.w = (uint)f2bf(o[6]) | ((uint)f2bf(o[7]) << 16);
            *(uint4*)(hbf + (size_t)node * 128 + g * 8) = st;
        } else {
            *(float4*)(out + (size_t)node * 128 + g * 8) =
                make_float4(v[0], v[1], v[2], v[3]);
            *(float4*)(out + (size_t)node * 128 + g * 8 + 4) =
                make_float4(v[4], v[5], v[6], v[7]);
        }
    }
}

extern "C" void kernel_launch(void* const* d_in, const int* in_sizes, int n_in,
                              void* d_out, int out_size, void* d_ws, size_t ws_size,
                              hipStream_t stream) {
    const float* x       = (const float*)d_in[0];
    const int*   ei      = (const int*)d_in[1];
    const int*   src     = ei;
    const int*   dst     = ei + E_EDGES;
    const float* W1_src  = (const float*)d_in[2];
    const float* W1_dst  = (const float*)d_in[3];
    const float* att1_s  = (const float*)d_in[4];
    const float* att1_d  = (const float*)d_in[5];
    const float* b1      = (const float*)d_in[6];
    const float* Wl1     = (const float*)d_in[7];
    const float* bl1     = (const float*)d_in[8];
    const float* gamma   = (const float*)d_in[9];
    const float* beta    = (const float*)d_in[10];
    const float* W2_src  = (const float*)d_in[11];
    const float* W2_dst  = (const float*)d_in[12];
    const float* att2_s  = (const float*)d_in[13];
    const float* att2_d  = (const float*)d_in[14];
    const float* b2      = (const float*)d_in[15];
    const float* Wl2     = (const float*)d_in[16];
    const float* bl2     = (const float*)d_in[17];
    float* out = (float*)d_out;

    // workspace layout
    char* p = (char*)d_ws;
    float* a_sd        = (float*)p;      p += (size_t)N_NODES * 8 * 4;
    int* offs          = (int*)p;        p += (size_t)N_NODES * 4;
    int* bucketCursor  = (int*)p;        p += 256 * 4;
    uint* pairs        = (uint*)p;       p += (size_t)NBUCK * BCAP * 4;
    ushort* degs       = (ushort*)p;     p += (size_t)N_NODES * 2;
    ushort* hbf        = (ushort*)p;     p += (size_t)N_NODES * 128 * 2;
    ushort* bufbf      = (ushort*)p;     p += (size_t)N_NODES * 256 * 2;
    ushort* Wt         = (ushort*)p;     p += (size_t)4 * 16384 * 2;
    ushort* Watt       = (ushort*)p;     p += (size_t)2 * 2048 * 2;
    ushort* srcSorted  = (ushort*)p;     p += (size_t)NBUCK * BCAP * 2;

    dim3 ggrid(2, (N_NODES + 63) / 64);
    int edge_blocks = (E_EDGES + 4095) / 4096;   // 196
    int wave_grid   = (N_NODES + 3) / 4;

    // -------- prep (weights + cursor zero), then CSR build --------
    prep_all_kernel<<<259, 256, 0, stream>>>(
        W1_src, Wl1, W1_dst, att1_s, att1_d,
        W2_src, Wl2, W2_dst, att2_s, att2_d, Wt, Watt, bucketCursor);
    bucket_scatter_kernel<<<edge_blocks, 256, 0, stream>>>(src, dst, bucketCursor, pairs, E_EDGES);
    bucket_sort_kernel<<<NBUCK, 256, 0, stream>>>(pairs, bucketCursor, offs, degs, srcSorted, N_NODES);

    // -------- layer 1 --------
    gemm_fused_kernel<0><<<ggrid, 256, 0, stream>>>(x, nullptr, Wt, Watt, bufbf, a_sd, N_NODES);
    aggregate_fused_kernel<0><<<wave_grid, 256, 0, stream>>>(
        srcSorted, offs, degs, bufbf, a_sd, b1, bl1, gamma, beta, hbf, nullptr, N_NODES);

    // -------- layer 2 --------
    gemm_fused_kernel<1><<<ggrid, 256, 0, stream>>>(nullptr, hbf, Wt, Watt, bufbf, a_sd, N_NODES);
    aggregate_fused_kernel<1><<<wave_grid, 256, 0, stream>>>(
        srcSorted, offs, degs, bufbf, a_sd, b2, bl2, nullptr, nullptr, nullptr, out, N_NODES);
}